// Round 5
// baseline (2566.661 us; speedup 1.0000x reference)
//
#include <hip/hip_runtime.h>
#include <hip/hip_bf16.h>
#include <math.h>

using bf16 = __hip_bfloat16;

typedef short s8v __attribute__((ext_vector_type(8)));   // 8 bf16 bit-pattern (4 VGPRs)
typedef float f4v __attribute__((ext_vector_type(4)));   // MFMA accumulator

// ---------------- problem dims ----------------
static constexpr int  BB  = 2048;
static constexpr int  IH  = 23, IW = 31;   // stage 1 spatial
static constexpr int  PH  = 11, PW = 15;   // after pool1
static constexpr int  QH  = 5,  QW = 7;    // after pool2
static constexpr long NSITE1 = (long)BB * IH * IW;   // 1,460,224 = 64*22,816
static constexpr long NSITE2 = (long)BB * PH * PW;   //   337,920 = 64*5,280
static constexpr long NSITE3 = (long)BB * QH * QW;   //    71,680 = 64*1,120

// ---------------- workspace layout (same total as round 1: 187,449,344 B) ----------------
static constexpr long OFF_S1 = 0,   OFF_Q1 = 64;
static constexpr long OFF_S2 = 128, OFF_Q2 = 192;
static constexpr long OFF_S3 = 256, OFF_Q3 = 320;
static constexpr long OFF_S4 = 384, OFF_Q4 = 512;
static constexpr long OFF_N1 = 640, OFF_N2 = 641;
static constexpr long OFF_SC1 = 704,  OFF_SH1 = 768;
static constexpr long OFF_SC2 = 832,  OFF_SH2 = 896;
static constexpr long OFF_SC3 = 960,  OFF_SH3 = 1024;
static constexpr long OFF_SC4 = 1088, OFF_SH4 = 1216;
static constexpr long OFF_M0 = 2048;
static constexpr long OFF_M1 = OFF_M0 + NSITE1;
static constexpr long OFF_M2 = OFF_M1 + NSITE2;
static constexpr long OFF_BF = 1871872;             // float offset where bf16 area starts
static constexpr long SZ_A   = 43253760L;           // bf16 elems per region
// bf16 weight stashes carved from dead phases of bufA/bufB (see launch ordering):
static constexpr long WB2_A  = 25000000L;  // [9][32][32]  = 9,216   (bufA past c1)
static constexpr long WB3_B  = 22000000L;  // [9][64][32]  = 18,432  (bufB past c3)
static constexpr long WB4_B  = 22100000L;  // [9][128][64] = 73,728  (bufB past c3)
static constexpr long WBL_A  = 20000000L;  // [9][4][768][32] = 884,736 (bufA past gout)
static constexpr long WFC1_B = 23000000L;  // [1024][8960] = 9,175,040 (bufB, live pool1->fc1)

__device__ __forceinline__ float sigmoidf_(float x) { return 1.f / (1.f + __expf(-x)); }
__device__ __forceinline__ float b2f(bf16 v) { return __bfloat162float(v); }
__device__ __forceinline__ bf16  f2b(float v) { return __float2bfloat16(v); }

// load 8 consecutive bf16 (16B aligned) -> 8 floats
__device__ __forceinline__ void ld8(const bf16* p, float* f) {
    union { uint4 u; unsigned short s[8]; } cv;
    cv.u = *(const uint4*)p;
#pragma unroll
    for (int i = 0; i < 8; i++) f[i] = __uint_as_float(((unsigned int)cv.s[i]) << 16);
}
// store 8 floats -> 8 consecutive bf16 (16B aligned)
__device__ __forceinline__ void st8(bf16* p, const float* f) {
    union { uint4 u; bf16 h[8]; } cv;
#pragma unroll
    for (int i = 0; i < 8; i++) cv.h[i] = f2b(f[i]);
    *(uint4*)p = cv.u;
}

// ---------------- weight convert+transpose: W[tap][cin][cout] f32 -> wb[tap][cout][cinp] bf16 ----------------
__global__ void cvt_w_k(const float* __restrict__ W, bf16* __restrict__ wb,
                        int CIN, int CINP, int COUT, int total) {
    int idx = blockIdx.x * 256 + threadIdx.x;
    if (idx >= total) return;
    int ci  = idx % CINP;
    int t2  = idx / CINP;
    int co  = t2 % COUT;
    int tap = t2 / COUT;
    wb[idx] = (ci < CIN) ? f2b(W[((long)(tap * CIN + ci)) * COUT + co]) : f2b(0.f);
}

// ---------------- LSTM weight: Wl[tap][cin][1024] f32 -> wbl3[tap][kk][n'=g*256+c][32] bf16 ----------------
// g: 0->i (col c), 1->o (col 512+c), 2->g (col 768+c). f-gate (col 256+c) dropped (c0=0).
__global__ void cvt_wl3_k(const float* __restrict__ Wl, bf16* __restrict__ wbl3) {
    int idx = blockIdx.x * 256 + threadIdx.x;
    if (idx >= 884736) return;
    int kidx = idx & 31;
    int n    = (idx >> 5) % 768;
    int kk   = (idx >> 5) / 768 % 4;
    int tap  = idx / (32 * 768 * 4);
    int g = n >> 8, c = n & 255;
    int col = (g == 0) ? c : (g == 1 ? 512 + c : 768 + c);
    int cin = kk * 32 + kidx;
    wbl3[idx] = f2b(Wl[((long)(tap * 128 + cin)) * 1024 + col]);
}

// ---------------- FC1 weight: lw1[k=c*35+hw][j] f32 -> wfc1[j][k'=hw*256+c] bf16 ----------------
__global__ void cvt_fc1_k(const float* __restrict__ lw1, bf16* __restrict__ wfc1) {
    long idx = (long)blockIdx.x * 256 + threadIdx.x;
    if (idx >= 9175040L) return;
    int c  = (int)(idx & 255);
    int hw = (int)((idx >> 8) % 35);
    int j  = (int)(idx / 8960);
    wfc1[idx] = f2b(lw1[(long)(c * 35 + hw) * 1024 + j]);
}

// ---------------- prep: int mask -> float, xm = bf16(x*m) ----------------
__global__ void prep_k(const float* __restrict__ x, const int* __restrict__ mask,
                       float* __restrict__ m0, bf16* __restrict__ xm) {
    long idx = (long)blockIdx.x * 256 + threadIdx.x;
    if (idx >= NSITE1) return;
    float m = (mask[idx] != 0) ? 1.f : 0.f;
    m0[idx] = m;
    xm[idx * 2 + 0] = f2b(x[idx * 2 + 0] * m);
    xm[idx * 2 + 1] = f2b(x[idx * 2 + 1] * m);
}

// ---------------- conv1: 2->16, one site per thread (uniform weight loads) ----------------
__global__ void conv1_k(const bf16* __restrict__ xm, const float* __restrict__ Wt,
                        const float* __restrict__ m0, bf16* __restrict__ out) {
    const int H = IH, W = IW;
    long site = (long)blockIdx.x * 256 + threadIdx.x;
    if (site >= NSITE1) return;
    float acc[16];
#pragma unroll
    for (int i = 0; i < 16; i++) acc[i] = 0.f;
    float mk = m0[site];
    if (mk > 0.f) {
        int w = (int)(site % W); int h = (int)((site / W) % H);
        for (int tap = 0; tap < 9; tap++) {
            int dh = tap / 3 - 1, dw = tap % 3 - 1;
            int nh = h + dh, nw = w + dw;
            if (nh < 0 || nh >= H || nw < 0 || nw >= W) continue;
            long ns = site + (long)dh * W + dw;
            float i0 = b2f(xm[ns * 2 + 0]), i1 = b2f(xm[ns * 2 + 1]);
            const float* wp = Wt + tap * 32;   // [2][16]
#pragma unroll
            for (int co = 0; co < 16; co++) acc[co] += i0 * wp[co] + i1 * wp[16 + co];
        }
    }
    st8(out + site * 16, acc);
    st8(out + site * 16 + 8, acc + 8);
}

// ---------------- MFMA direct conv 3x3 SAME ----------------
template<int CIN, int CINP, int COUT, int KK, int MT_W, int NT_W, int H, int W>
__global__ void conv_mfma(const bf16* __restrict__ in, const bf16* __restrict__ wb,
                          const float* __restrict__ mask, bf16* __restrict__ out) {
    constexpr int NT = COUT / 16;
    constexpr int NWN = NT / NT_W;            // waves along N
    const int tid = threadIdx.x;
    const int wv = tid >> 6;
    const int L  = tid & 63;
    const int q  = (L >> 4);                  // quad
    const int lm = L & 15;
    const int wn = wv % NWN;
    const int wm = wv / NWN;
    const int mt0 = wm * MT_W;
    const long base = (long)blockIdx.x * 64;

    int hh[MT_W], ww[MT_W];
    long siteA[MT_W];
#pragma unroll
    for (int i = 0; i < MT_W; i++) {
        long s = base + (mt0 + i) * 16 + lm;
        siteA[i] = s;
        int wq = (int)(s % W); long t2 = s / W;
        hh[i] = (int)(t2 % H); ww[i] = wq;
    }

    f4v acc[MT_W][NT_W];
#pragma unroll
    for (int i = 0; i < MT_W; i++)
#pragma unroll
        for (int j = 0; j < NT_W; j++) acc[i][j] = (f4v){0.f, 0.f, 0.f, 0.f};

    for (int tap = 0; tap < 9; tap++) {
        const int dh = tap / 3 - 1, dw = tap % 3 - 1;
#pragma unroll
        for (int kk = 0; kk < KK; kk++) {
            s8v a[MT_W];
#pragma unroll
            for (int i = 0; i < MT_W; i++) {
                int nh = hh[i] + dh, nw = ww[i] + dw;
                bool ok = (nh >= 0) & (nh < H) & (nw >= 0) & (nw < W);
                a[i] = (s8v){0, 0, 0, 0, 0, 0, 0, 0};
                if (ok) {
                    long ns = siteA[i] + (long)dh * W + dw;
                    a[i] = *(const s8v*)(in + ns * CIN + kk * 32 + q * 8);
                }
            }
#pragma unroll
            for (int j = 0; j < NT_W; j++) {
                int co = (wn * NT_W + j) * 16 + lm;
                s8v b = *(const s8v*)(wb + ((long)(tap * COUT + co)) * CINP + kk * 32 + q * 8);
#pragma unroll
                for (int i = 0; i < MT_W; i++)
                    acc[i][j] = __builtin_amdgcn_mfma_f32_16x16x32_bf16(a[i], b, acc[i][j], 0, 0, 0);
            }
        }
    }
#pragma unroll
    for (int i = 0; i < MT_W; i++) {
#pragma unroll
        for (int r = 0; r < 4; r++) {
            long so = base + (mt0 + i) * 16 + q * 4 + r;
            float mk = mask[so];
#pragma unroll
            for (int j = 0; j < NT_W; j++) {
                int co = (wn * NT_W + j) * 16 + lm;
                out[so * COUT + co] = f2b(mk > 0.f ? acc[i][j][r] : 0.f);
            }
        }
    }
}

// ---------------- BN stats (bf16x8 vector loads) ----------------
template<int C>
__global__ void bn_stats(const bf16* __restrict__ v, const float* __restrict__ mask,
                         float* __restrict__ sum, float* __restrict__ sumsq,
                         float* __restrict__ count, long nsites) {
    __shared__ float s_sum[C], s_ss[C];
    __shared__ float s_cnt;
    int tid = threadIdx.x;
    if (tid < C) { s_sum[tid] = 0.f; s_ss[tid] = 0.f; }
    if (tid == 0) s_cnt = 0.f;
    __syncthreads();
    const long total8 = nsites * C / 8;
    const long stride = (long)gridDim.x * 256;
    const int c0 = (int)((((long)blockIdx.x * 256 + tid) * 8) % C);  // fixed per thread
    float ls[8], lss[8];
#pragma unroll
    for (int i = 0; i < 8; i++) { ls[i] = 0.f; lss[i] = 0.f; }
    float lc = 0.f;
    for (long e8 = (long)blockIdx.x * 256 + tid; e8 < total8; e8 += stride) {
        long e0 = e8 * 8;
        float f[8];
        ld8(v + e0, f);
#pragma unroll
        for (int i = 0; i < 8; i++) { ls[i] += f[i]; lss[i] += f[i] * f[i]; }
        if (count != nullptr && c0 == 0) lc += (mask[e0 / C] > 0.f) ? 1.f : 0.f;
    }
#pragma unroll
    for (int i = 0; i < 8; i++) {
        atomicAdd(&s_sum[c0 + i], ls[i]);
        atomicAdd(&s_ss[c0 + i], lss[i]);
    }
    if (count != nullptr && c0 == 0) atomicAdd(&s_cnt, lc);
    __syncthreads();
    if (tid < C) { atomicAdd(&sum[tid], s_sum[tid]); atomicAdd(&sumsq[tid], s_ss[tid]); }
    if (count != nullptr && tid == 0) atomicAdd(count, s_cnt);
}

template<int C>
__global__ void bn_param(const float* __restrict__ sum, const float* __restrict__ ss,
                         const float* __restrict__ count,
                         const float* __restrict__ g, const float* __restrict__ b,
                         float* __restrict__ scale, float* __restrict__ shift) {
    int c = threadIdx.x;
    if (c >= C) return;
    float n = fmaxf(count[0], 1.f);
    float mean = sum[c] / n;
    float var  = ss[c] / n - mean * mean;
    float sc = (1.f / sqrtf(var + 1e-4f)) * g[c];
    scale[c] = sc;
    shift[c] = b[c] - mean * sc;
}

// ---------------- BN apply (+ReLU, masked), in-place, bf16x8 ----------------
template<int C>
__global__ void bn_apply(bf16* __restrict__ v, const float* __restrict__ mask,
                         const float* __restrict__ scale, const float* __restrict__ shift,
                         long nsites) {
    long i8 = (long)blockIdx.x * 256 + threadIdx.x;
    if (i8 >= nsites * C / 8) return;
    long e0 = i8 * 8;
    int c0 = (int)(e0 % C);
    long site = e0 / C;
    float mk = mask[site];
    float f[8], o[8];
    ld8(v + e0, f);
#pragma unroll
    for (int i = 0; i < 8; i++)
        o[i] = (mk > 0.f) ? fmaxf(f[i] * scale[c0 + i] + shift[c0 + i], 0.f) : 0.f;
    st8(v + e0, o);
}

// ---------------- maxpool 3x3 stride 2 VALID + mask pool, bf16x8 ----------------
template<int C>
__global__ void maxpool_k(const bf16* __restrict__ in, const float* __restrict__ min_,
                          bf16* __restrict__ out, float* __restrict__ mout,
                          int B, int H, int W, int OH, int OW) {
    long i8 = (long)blockIdx.x * 256 + threadIdx.x;
    long total8 = (long)B * OH * OW * C / 8;
    if (i8 >= total8) return;
    long e0 = i8 * 8;
    int c0 = (int)(e0 % C);
    long osite = e0 / C;
    int ow = (int)(osite % OW); long t2 = osite / OW; int oh = (int)(t2 % OH); long b = t2 / OH;
    float mm = 0.f, p[8];
#pragma unroll
    for (int i = 0; i < 8; i++) p[i] = -1e30f;
    for (int kh = 0; kh < 3; kh++)
    for (int kw = 0; kw < 3; kw++) {
        int h = oh * 2 + kh, w = ow * 2 + kw;
        long is = ((long)b * H + h) * W + w;
        float mv = min_[is];
        if (mv > 0.f) {
            mm = 1.f;
            float f[8];
            ld8(in + is * C + c0, f);
#pragma unroll
            for (int i = 0; i < 8; i++) p[i] = fmaxf(p[i], f[i]);
        }
    }
    float o[8];
#pragma unroll
    for (int i = 0; i < 8; i++) o[i] = (mm > 0.f) ? p[i] : 0.f;
    st8(out + e0, o);
    if (c0 == 0) mout[osite] = mm;
}

// ---------------- ConvLSTM gates via MFMA, coalesced-slab B ----------------
// Block = 64 sites (grid NSITE3/64), 4 waves: wv -> (wm = wv>>1, wn = wv&1).
// Wave tile: 2 m-tiles (sites (wm*2+i)*16) x 12 n-tiles per pass.
// N organized as n' = g*256 + c in wbl3[tap][kk][n'][32] (contiguous 1KB per B-frag
// wave-load -> fully coalesced). Pass p covers channel chunks cc = p*8 + wn*4 + j.
__global__ void gates_mfma(const bf16* __restrict__ p2, const bf16* __restrict__ wbl3,
                           const float* __restrict__ bl, const float* __restrict__ m2,
                           bf16* __restrict__ gout) {
    const int tid = threadIdx.x;
    const int wv = tid >> 6;
    const int L  = tid & 63;
    const int q  = L >> 4;
    const int lm = L & 15;
    const int wm = wv >> 1, wn = wv & 1;
    const long base = (long)blockIdx.x * 64;

    int hh[2], ww[2];
    long siteA[2];
#pragma unroll
    for (int i = 0; i < 2; i++) {
        long s = base + (wm * 2 + i) * 16 + lm;
        siteA[i] = s;
        ww[i] = (int)(s % QW); hh[i] = (int)((s / QW) % QH);
    }

    for (int pass = 0; pass < 2; pass++) {
        f4v acc[2][4][3];   // [mtile][c-chunk j][gate i/o/g]
#pragma unroll
        for (int i = 0; i < 2; i++)
#pragma unroll
            for (int j = 0; j < 4; j++)
#pragma unroll
                for (int g = 0; g < 3; g++) acc[i][j][g] = (f4v){0.f, 0.f, 0.f, 0.f};

        for (int tap = 0; tap < 9; tap++) {
            const int dh = tap / 3 - 1, dw = tap % 3 - 1;
#pragma unroll
            for (int kk = 0; kk < 4; kk++) {
                s8v a[2];
#pragma unroll
                for (int i = 0; i < 2; i++) {
                    int nh = hh[i] + dh, nw = ww[i] + dw;
                    bool ok = (nh >= 0) & (nh < QH) & (nw >= 0) & (nw < QW);
                    a[i] = (s8v){0, 0, 0, 0, 0, 0, 0, 0};
                    if (ok) {
                        long ns = siteA[i] + (long)dh * QW + dw;
                        a[i] = *(const s8v*)(p2 + ns * 128 + kk * 32 + q * 8);
                    }
                }
                const bf16* slab = wbl3 + ((long)(tap * 4 + kk)) * 768 * 32 + (long)q * 8;
#pragma unroll
                for (int j = 0; j < 4; j++) {
                    int cc = pass * 8 + wn * 4 + j;          // channel chunk 0..15
#pragma unroll
                    for (int g = 0; g < 3; g++) {
                        int n = g * 256 + cc * 16 + lm;
                        s8v b = *(const s8v*)(slab + (long)n * 32);
#pragma unroll
                        for (int i = 0; i < 2; i++)
                            acc[i][j][g] = __builtin_amdgcn_mfma_f32_16x16x32_bf16(a[i], b, acc[i][j][g], 0, 0, 0);
                    }
                }
            }
        }
        // epilogue: all in registers; D[row=q*4+r][col=lm]
#pragma unroll
        for (int j = 0; j < 4; j++) {
            int c = (pass * 8 + wn * 4 + j) * 16 + lm;
            float bi = bl[c], bo = bl[512 + c], bg = bl[768 + c];
#pragma unroll
            for (int i = 0; i < 2; i++) {
#pragma unroll
                for (int r = 0; r < 4; r++) {
                    long so = base + (wm * 2 + i) * 16 + q * 4 + r;
                    float m = m2[so];
                    float val = 0.f;
                    if (m > 0.f) {
                        float iv = acc[i][j][0][r] + bi;
                        float ov = acc[i][j][1][r] + bo;
                        float gv = acc[i][j][2][r] + bg;
                        float ct = sigmoidf_(iv) * tanhf(gv);
                        val = sigmoidf_(ov) * tanhf(ct);
                    }
                    gout[so * 256 + c] = f2b(val);
                }
            }
        }
    }
}

// ---------------- FC1 via MFMA ----------------
__global__ void fc1_mfma(const bf16* __restrict__ A, const bf16* __restrict__ Wt,
                         const float* __restrict__ lb1, bf16* __restrict__ y1) {
    const int tid = threadIdx.x;
    const int wv = tid >> 6;
    const int L  = tid & 63;
    const int q  = L >> 4, lm = L & 15;
    const int wm = wv >> 1, wn = wv & 1;
    const int bm = blockIdx.x & 31;
    const int bn = blockIdx.x >> 5;
    const int m0 = bm * 64 + wm * 32;
    const int n0 = bn * 64 + wn * 32;

    f4v acc[2][2];
#pragma unroll
    for (int i = 0; i < 2; i++)
#pragma unroll
        for (int j = 0; j < 2; j++) acc[i][j] = (f4v){0.f, 0.f, 0.f, 0.f};

    const bf16* a0p = A  + (long)(m0 + lm) * 8960 + q * 8;
    const bf16* a1p = a0p + (long)16 * 8960;
    const bf16* b0p = Wt + (long)(n0 + lm) * 8960 + q * 8;
    const bf16* b1p = b0p + (long)16 * 8960;

#pragma unroll 2
    for (int k0 = 0; k0 < 8960; k0 += 32) {
        s8v a0 = *(const s8v*)(a0p + k0);
        s8v a1 = *(const s8v*)(a1p + k0);
        s8v b0 = *(const s8v*)(b0p + k0);
        s8v b1 = *(const s8v*)(b1p + k0);
        acc[0][0] = __builtin_amdgcn_mfma_f32_16x16x32_bf16(a0, b0, acc[0][0], 0, 0, 0);
        acc[0][1] = __builtin_amdgcn_mfma_f32_16x16x32_bf16(a0, b1, acc[0][1], 0, 0, 0);
        acc[1][0] = __builtin_amdgcn_mfma_f32_16x16x32_bf16(a1, b0, acc[1][0], 0, 0, 0);
        acc[1][1] = __builtin_amdgcn_mfma_f32_16x16x32_bf16(a1, b1, acc[1][1], 0, 0, 0);
    }
#pragma unroll
    for (int i = 0; i < 2; i++) {
#pragma unroll
        for (int j = 0; j < 2; j++) {
            int nn = n0 + j * 16 + lm;
            float bias = lb1[nn];
#pragma unroll
            for (int r = 0; r < 4; r++) {
                int mm = m0 + i * 16 + q * 4 + r;
                y1[(long)mm * 1024 + nn] = f2b(fmaxf(acc[i][j][r] + bias, 0.f));
            }
        }
    }
}

// ---------------- FC2 ----------------
__global__ void fc2_k(const bf16* __restrict__ y1, const float* __restrict__ lw2,
                      const float* __restrict__ lb2, float* __restrict__ out) {
    long idx = (long)blockIdx.x * 256 + threadIdx.x;
    long total = (long)BB * 420;
    if (idx >= total) return;
    int j = (int)(idx % 420); long b = idx / 420;
    float acc = lb2[j];
    const bf16* yr = y1 + b * 1024;
    for (int k8 = 0; k8 < 1024; k8 += 8) {
        float f[8];
        ld8(yr + k8, f);
#pragma unroll
        for (int i = 0; i < 8; i++) acc += f[i] * lw2[(long)(k8 + i) * 420 + j];
    }
    out[idx] = acc;
}

// ---------------- launch ----------------
extern "C" void kernel_launch(void* const* d_in, const int* in_sizes, int n_in,
                              void* d_out, int out_size, void* d_ws, size_t ws_size,
                              hipStream_t stream) {
    const float* x    = (const float*)d_in[0];
    const int*   mask = (const int*)d_in[1];
    const float* W1 = (const float*)d_in[2];
    const float* g1 = (const float*)d_in[3];
    const float* b1 = (const float*)d_in[4];
    const float* W2 = (const float*)d_in[5];
    const float* g2 = (const float*)d_in[6];
    const float* b2 = (const float*)d_in[7];
    const float* W3 = (const float*)d_in[8];
    const float* g3 = (const float*)d_in[9];
    const float* b3 = (const float*)d_in[10];
    const float* W4 = (const float*)d_in[11];
    const float* g4 = (const float*)d_in[12];
    const float* b4 = (const float*)d_in[13];
    const float* Wl = (const float*)d_in[14];
    const float* bl = (const float*)d_in[15];
    const float* lw1 = (const float*)d_in[16];
    const float* lb1 = (const float*)d_in[17];
    const float* lw2 = (const float*)d_in[18];
    const float* lb2 = (const float*)d_in[19];
    float* out = (float*)d_out;

    float* ws = (float*)d_ws;
    float* m0 = ws + OFF_M0;
    float* m1 = ws + OFF_M1;
    float* m2 = ws + OFF_M2;
    bf16* bufA = (bf16*)(ws + OFF_BF);
    bf16* bufB = bufA + SZ_A;

    bf16* c1   = bufA;            // [NSITE1,16]
    bf16* xm   = bufB;            // [NSITE1,2]  (dead after conv1)
    bf16* c2   = bufB;            // [NSITE1,32]
    bf16* p1   = bufA;            // [NSITE2,32]
    bf16* c3   = bufB;            // [NSITE2,64]
    bf16* c4   = bufA;            // [NSITE2,128]
    bf16* p2   = bufB;            // [NSITE3,128]
    bf16* gout = bufA;            // [NSITE3,256] == A[2048][8960]
    bf16* y1   = bufB;            // [2048,1024]
    bf16* wb2  = bufA + WB2_A;
    bf16* wb3  = bufB + WB3_B;
    bf16* wb4  = bufB + WB4_B;
    bf16* wbl3 = bufA + WBL_A;
    bf16* wfc1 = bufB + WFC1_B;

    hipMemsetAsync(ws, 0, 4096, stream);   // BN stat accumulators

    prep_k<<<(int)((NSITE1 + 255) / 256), 256, 0, stream>>>(x, mask, m0, xm);
    cvt_w_k<<<(9216 + 255) / 256, 256, 0, stream>>>(W2, wb2, 16, 32, 32, 9216);

    conv1_k<<<(int)((NSITE1 + 255) / 256), 256, 0, stream>>>(xm, W1, m0, c1);
    bn_stats<16><<<1280, 256, 0, stream>>>(c1, m0, ws + OFF_S1, ws + OFF_Q1, ws + OFF_N1, NSITE1);
    bn_param<16><<<1, 16, 0, stream>>>(ws + OFF_S1, ws + OFF_Q1, ws + OFF_N1, g1, b1, ws + OFF_SC1, ws + OFF_SH1);
    bn_apply<16><<<(int)(NSITE1 * 16 / 8 / 256), 256, 0, stream>>>(c1, m0, ws + OFF_SC1, ws + OFF_SH1, NSITE1);

    conv_mfma<16, 32, 32, 1, 2, 1, IH, IW><<<(int)(NSITE1 / 64), 256, 0, stream>>>(c1, wb2, m0, c2);
    bn_stats<32><<<1280, 256, 0, stream>>>(c2, m0, ws + OFF_S2, ws + OFF_Q2, nullptr, NSITE1);
    bn_param<32><<<1, 32, 0, stream>>>(ws + OFF_S2, ws + OFF_Q2, ws + OFF_N1, g2, b2, ws + OFF_SC2, ws + OFF_SH2);
    bn_apply<32><<<(int)(NSITE1 * 32 / 8 / 256), 256, 0, stream>>>(c2, m0, ws + OFF_SC2, ws + OFF_SH2, NSITE1);

    maxpool_k<32><<<(int)(NSITE2 * 32 / 8 / 256), 256, 0, stream>>>(c2, m0, p1, m1, BB, IH, IW, PH, PW);

    // c2 (bufB) dead: convert wb3, wb4, wfc1 into bufB slack
    cvt_w_k<<<(18432 + 255) / 256, 256, 0, stream>>>(W3, wb3, 32, 32, 64, 18432);
    cvt_w_k<<<(73728 + 255) / 256, 256, 0, stream>>>(W4, wb4, 64, 64, 128, 73728);
    cvt_fc1_k<<<(int)((9175040L + 255) / 256), 256, 0, stream>>>(lw1, wfc1);

    conv_mfma<32, 32, 64, 1, 4, 1, PH, PW><<<(int)(NSITE2 / 64), 256, 0, stream>>>(p1, wb3, m1, c3);
    bn_stats<64><<<1280, 256, 0, stream>>>(c3, m1, ws + OFF_S3, ws + OFF_Q3, ws + OFF_N2, NSITE2);
    bn_param<64><<<1, 64, 0, stream>>>(ws + OFF_S3, ws + OFF_Q3, ws + OFF_N2, g3, b3, ws + OFF_SC3, ws + OFF_SH3);
    bn_apply<64><<<(int)(NSITE2 * 64 / 8 / 256), 256, 0, stream>>>(c3, m1, ws + OFF_SC3, ws + OFF_SH3, NSITE2);

    conv_mfma<64, 64, 128, 2, 4, 2, PH, PW><<<(int)(NSITE2 / 64), 256, 0, stream>>>(c3, wb4, m1, c4);
    bn_stats<128><<<1280, 256, 0, stream>>>(c4, m1, ws + OFF_S4, ws + OFF_Q4, nullptr, NSITE2);
    bn_param<128><<<1, 128, 0, stream>>>(ws + OFF_S4, ws + OFF_Q4, ws + OFF_N2, g4, b4, ws + OFF_SC4, ws + OFF_SH4);
    bn_apply<128><<<(int)(NSITE2 * 128 / 8 / 256), 256, 0, stream>>>(c4, m1, ws + OFF_SC4, ws + OFF_SH4, NSITE2);

    maxpool_k<128><<<(int)(NSITE3 * 128 / 8 / 256), 256, 0, stream>>>(c4, m1, p2, m2, BB, PH, PW, QH, QW);

    // c4 (bufA) dead: convert wbl3 into bufA past gout's end
    cvt_wl3_k<<<(884736 + 255) / 256, 256, 0, stream>>>(Wl, wbl3);

    gates_mfma<<<(int)(NSITE3 / 64), 256, 0, stream>>>(p2, wbl3, bl, m2, gout);

    fc1_mfma<<<512, 256, 0, stream>>>(gout, wfc1, lb1, y1);

    fc2_k<<<(int)((BB * 420L + 255) / 256), 256, 0, stream>>>(y1, lw2, lb2, out);
}

// Round 6
// 2179.327 us; speedup vs baseline: 1.1777x; 1.1777x over previous
//
#include <hip/hip_runtime.h>
#include <hip/hip_bf16.h>
#include <math.h>

using bf16 = __hip_bfloat16;

typedef short s8v __attribute__((ext_vector_type(8)));   // 8 bf16 bit-pattern (4 VGPRs)
typedef float f4v __attribute__((ext_vector_type(4)));   // MFMA accumulator

// ---------------- problem dims ----------------
static constexpr int  BB  = 2048;
static constexpr int  IH  = 23, IW = 31;   // stage 1 spatial
static constexpr int  PH  = 11, PW = 15;   // after pool1
static constexpr int  QH  = 5,  QW = 7;    // after pool2
static constexpr long NSITE1 = (long)BB * IH * IW;   // 1,460,224 = 64*22,816
static constexpr long NSITE2 = (long)BB * PH * PW;   //   337,920 = 64*5,280
static constexpr long NSITE3 = (long)BB * QH * QW;   //    71,680 = 32*2,240

// ---------------- workspace layout (same total as round 1: 187,449,344 B) ----------------
static constexpr long OFF_S1 = 0,   OFF_Q1 = 64;
static constexpr long OFF_S2 = 128, OFF_Q2 = 192;
static constexpr long OFF_S3 = 256, OFF_Q3 = 320;
static constexpr long OFF_S4 = 384, OFF_Q4 = 512;
static constexpr long OFF_N1 = 640, OFF_N2 = 641;
static constexpr long OFF_SC1 = 704,  OFF_SH1 = 768;
static constexpr long OFF_SC2 = 832,  OFF_SH2 = 896;
static constexpr long OFF_SC3 = 960,  OFF_SH3 = 1024;
static constexpr long OFF_SC4 = 1088, OFF_SH4 = 1216;
static constexpr long OFF_M0 = 2048;
static constexpr long OFF_M1 = OFF_M0 + NSITE1;
static constexpr long OFF_M2 = OFF_M1 + NSITE2;
static constexpr long OFF_BF = 1871872;             // float offset where bf16 area starts
static constexpr long SZ_A   = 43253760L;           // bf16 elems per region
// bf16 weight stashes carved from dead phases of bufA/bufB (see launch ordering):
static constexpr long WB2_A  = 25000000L;  // [9][32][32]  = 9,216   (bufA past c1)
static constexpr long WB3_B  = 22000000L;  // [9][64][32]  = 18,432  (bufB past c3)
static constexpr long WB4_B  = 22100000L;  // [9][128][64] = 73,728  (bufB past c3)
static constexpr long WBL_A  = 20000000L;  // [9][4][768][32] = 884,736 (bufA past gout)
static constexpr long WFC1_B = 23000000L;  // [1024][8960] = 9,175,040 (bufB, live pool1->fc1)

__device__ __forceinline__ float sigmoidf_(float x) { return 1.f / (1.f + __expf(-x)); }
__device__ __forceinline__ float b2f(bf16 v) { return __bfloat162float(v); }
__device__ __forceinline__ bf16  f2b(float v) { return __float2bfloat16(v); }

// load 8 consecutive bf16 (16B aligned) -> 8 floats
__device__ __forceinline__ void ld8(const bf16* p, float* f) {
    union { uint4 u; unsigned short s[8]; } cv;
    cv.u = *(const uint4*)p;
#pragma unroll
    for (int i = 0; i < 8; i++) f[i] = __uint_as_float(((unsigned int)cv.s[i]) << 16);
}
// store 8 floats -> 8 consecutive bf16 (16B aligned)
__device__ __forceinline__ void st8(bf16* p, const float* f) {
    union { uint4 u; bf16 h[8]; } cv;
#pragma unroll
    for (int i = 0; i < 8; i++) cv.h[i] = f2b(f[i]);
    *(uint4*)p = cv.u;
}

// ---------------- weight convert+transpose: W[tap][cin][cout] f32 -> wb[tap][cout][cinp] bf16 ----------------
__global__ void cvt_w_k(const float* __restrict__ W, bf16* __restrict__ wb,
                        int CIN, int CINP, int COUT, int total) {
    int idx = blockIdx.x * 256 + threadIdx.x;
    if (idx >= total) return;
    int ci  = idx % CINP;
    int t2  = idx / CINP;
    int co  = t2 % COUT;
    int tap = t2 / COUT;
    wb[idx] = (ci < CIN) ? f2b(W[((long)(tap * CIN + ci)) * COUT + co]) : f2b(0.f);
}

// ---------------- LSTM weight: Wl[tap][cin][1024] f32 -> wbl3[tap][kk][n'=g*256+c][32] bf16 ----------------
// g: 0->i (col c), 1->o (col 512+c), 2->g (col 768+c). f-gate (col 256+c) dropped (c0=0).
__global__ void cvt_wl3_k(const float* __restrict__ Wl, bf16* __restrict__ wbl3) {
    int idx = blockIdx.x * 256 + threadIdx.x;
    if (idx >= 884736) return;
    int kidx = idx & 31;
    int n    = (idx >> 5) % 768;
    int kk   = (idx >> 5) / 768 % 4;
    int tap  = idx / (32 * 768 * 4);
    int g = n >> 8, c = n & 255;
    int col = (g == 0) ? c : (g == 1 ? 512 + c : 768 + c);
    int cin = kk * 32 + kidx;
    wbl3[idx] = f2b(Wl[((long)(tap * 128 + cin)) * 1024 + col]);
}

// ---------------- FC1 weight: lw1[k=c*35+hw][j] f32 -> wfc1[j][k'=hw*256+c] bf16 ----------------
__global__ void cvt_fc1_k(const float* __restrict__ lw1, bf16* __restrict__ wfc1) {
    long idx = (long)blockIdx.x * 256 + threadIdx.x;
    if (idx >= 9175040L) return;
    int c  = (int)(idx & 255);
    int hw = (int)((idx >> 8) % 35);
    int j  = (int)(idx / 8960);
    wfc1[idx] = f2b(lw1[(long)(c * 35 + hw) * 1024 + j]);
}

// ---------------- prep: int mask -> float, xm = bf16(x*m) ----------------
__global__ void prep_k(const float* __restrict__ x, const int* __restrict__ mask,
                       float* __restrict__ m0, bf16* __restrict__ xm) {
    long idx = (long)blockIdx.x * 256 + threadIdx.x;
    if (idx >= NSITE1) return;
    float m = (mask[idx] != 0) ? 1.f : 0.f;
    m0[idx] = m;
    xm[idx * 2 + 0] = f2b(x[idx * 2 + 0] * m);
    xm[idx * 2 + 1] = f2b(x[idx * 2 + 1] * m);
}

// ---------------- conv1: 2->16, one site per thread (uniform weight loads) ----------------
__global__ void conv1_k(const bf16* __restrict__ xm, const float* __restrict__ Wt,
                        const float* __restrict__ m0, bf16* __restrict__ out) {
    const int H = IH, W = IW;
    long site = (long)blockIdx.x * 256 + threadIdx.x;
    if (site >= NSITE1) return;
    float acc[16];
#pragma unroll
    for (int i = 0; i < 16; i++) acc[i] = 0.f;
    float mk = m0[site];
    if (mk > 0.f) {
        int w = (int)(site % W); int h = (int)((site / W) % H);
        for (int tap = 0; tap < 9; tap++) {
            int dh = tap / 3 - 1, dw = tap % 3 - 1;
            int nh = h + dh, nw = w + dw;
            if (nh < 0 || nh >= H || nw < 0 || nw >= W) continue;
            long ns = site + (long)dh * W + dw;
            float i0 = b2f(xm[ns * 2 + 0]), i1 = b2f(xm[ns * 2 + 1]);
            const float* wp = Wt + tap * 32;   // [2][16]
#pragma unroll
            for (int co = 0; co < 16; co++) acc[co] += i0 * wp[co] + i1 * wp[16 + co];
        }
    }
    st8(out + site * 16, acc);
    st8(out + site * 16 + 8, acc + 8);
}

// ---------------- MFMA direct conv 3x3 SAME ----------------
template<int CIN, int CINP, int COUT, int KK, int MT_W, int NT_W, int H, int W>
__global__ void conv_mfma(const bf16* __restrict__ in, const bf16* __restrict__ wb,
                          const float* __restrict__ mask, bf16* __restrict__ out) {
    constexpr int NT = COUT / 16;
    constexpr int NWN = NT / NT_W;            // waves along N
    const int tid = threadIdx.x;
    const int wv = tid >> 6;
    const int L  = tid & 63;
    const int q  = (L >> 4);                  // quad
    const int lm = L & 15;
    const int wn = wv % NWN;
    const int wm = wv / NWN;
    const int mt0 = wm * MT_W;
    const long base = (long)blockIdx.x * 64;

    int hh[MT_W], ww[MT_W];
    long siteA[MT_W];
#pragma unroll
    for (int i = 0; i < MT_W; i++) {
        long s = base + (mt0 + i) * 16 + lm;
        siteA[i] = s;
        int wq = (int)(s % W); long t2 = s / W;
        hh[i] = (int)(t2 % H); ww[i] = wq;
    }

    f4v acc[MT_W][NT_W];
#pragma unroll
    for (int i = 0; i < MT_W; i++)
#pragma unroll
        for (int j = 0; j < NT_W; j++) acc[i][j] = (f4v){0.f, 0.f, 0.f, 0.f};

    for (int tap = 0; tap < 9; tap++) {
        const int dh = tap / 3 - 1, dw = tap % 3 - 1;
#pragma unroll
        for (int kk = 0; kk < KK; kk++) {
            s8v a[MT_W];
#pragma unroll
            for (int i = 0; i < MT_W; i++) {
                int nh = hh[i] + dh, nw = ww[i] + dw;
                bool ok = (nh >= 0) & (nh < H) & (nw >= 0) & (nw < W);
                a[i] = (s8v){0, 0, 0, 0, 0, 0, 0, 0};
                if (ok) {
                    long ns = siteA[i] + (long)dh * W + dw;
                    a[i] = *(const s8v*)(in + ns * CIN + kk * 32 + q * 8);
                }
            }
#pragma unroll
            for (int j = 0; j < NT_W; j++) {
                int co = (wn * NT_W + j) * 16 + lm;
                s8v b = *(const s8v*)(wb + ((long)(tap * COUT + co)) * CINP + kk * 32 + q * 8);
#pragma unroll
                for (int i = 0; i < MT_W; i++)
                    acc[i][j] = __builtin_amdgcn_mfma_f32_16x16x32_bf16(a[i], b, acc[i][j], 0, 0, 0);
            }
        }
    }
#pragma unroll
    for (int i = 0; i < MT_W; i++) {
#pragma unroll
        for (int r = 0; r < 4; r++) {
            long so = base + (mt0 + i) * 16 + q * 4 + r;
            float mk = mask[so];
#pragma unroll
            for (int j = 0; j < NT_W; j++) {
                int co = (wn * NT_W + j) * 16 + lm;
                out[so * COUT + co] = f2b(mk > 0.f ? acc[i][j][r] : 0.f);
            }
        }
    }
}

// ---------------- BN stats (bf16x8 vector loads) ----------------
template<int C>
__global__ void bn_stats(const bf16* __restrict__ v, const float* __restrict__ mask,
                         float* __restrict__ sum, float* __restrict__ sumsq,
                         float* __restrict__ count, long nsites) {
    __shared__ float s_sum[C], s_ss[C];
    __shared__ float s_cnt;
    int tid = threadIdx.x;
    if (tid < C) { s_sum[tid] = 0.f; s_ss[tid] = 0.f; }
    if (tid == 0) s_cnt = 0.f;
    __syncthreads();
    const long total8 = nsites * C / 8;
    const long stride = (long)gridDim.x * 256;
    const int c0 = (int)((((long)blockIdx.x * 256 + tid) * 8) % C);  // fixed per thread
    float ls[8], lss[8];
#pragma unroll
    for (int i = 0; i < 8; i++) { ls[i] = 0.f; lss[i] = 0.f; }
    float lc = 0.f;
    for (long e8 = (long)blockIdx.x * 256 + tid; e8 < total8; e8 += stride) {
        long e0 = e8 * 8;
        float f[8];
        ld8(v + e0, f);
#pragma unroll
        for (int i = 0; i < 8; i++) { ls[i] += f[i]; lss[i] += f[i] * f[i]; }
        if (count != nullptr && c0 == 0) lc += (mask[e0 / C] > 0.f) ? 1.f : 0.f;
    }
#pragma unroll
    for (int i = 0; i < 8; i++) {
        atomicAdd(&s_sum[c0 + i], ls[i]);
        atomicAdd(&s_ss[c0 + i], lss[i]);
    }
    if (count != nullptr && c0 == 0) atomicAdd(&s_cnt, lc);
    __syncthreads();
    if (tid < C) { atomicAdd(&sum[tid], s_sum[tid]); atomicAdd(&sumsq[tid], s_ss[tid]); }
    if (count != nullptr && tid == 0) atomicAdd(count, s_cnt);
}

template<int C>
__global__ void bn_param(const float* __restrict__ sum, const float* __restrict__ ss,
                         const float* __restrict__ count,
                         const float* __restrict__ g, const float* __restrict__ b,
                         float* __restrict__ scale, float* __restrict__ shift) {
    int c = threadIdx.x;
    if (c >= C) return;
    float n = fmaxf(count[0], 1.f);
    float mean = sum[c] / n;
    float var  = ss[c] / n - mean * mean;
    float sc = (1.f / sqrtf(var + 1e-4f)) * g[c];
    scale[c] = sc;
    shift[c] = b[c] - mean * sc;
}

// ---------------- BN apply (+ReLU, masked), in-place, bf16x8 ----------------
template<int C>
__global__ void bn_apply(bf16* __restrict__ v, const float* __restrict__ mask,
                         const float* __restrict__ scale, const float* __restrict__ shift,
                         long nsites) {
    long i8 = (long)blockIdx.x * 256 + threadIdx.x;
    if (i8 >= nsites * C / 8) return;
    long e0 = i8 * 8;
    int c0 = (int)(e0 % C);
    long site = e0 / C;
    float mk = mask[site];
    float f[8], o[8];
    ld8(v + e0, f);
#pragma unroll
    for (int i = 0; i < 8; i++)
        o[i] = (mk > 0.f) ? fmaxf(f[i] * scale[c0 + i] + shift[c0 + i], 0.f) : 0.f;
    st8(v + e0, o);
}

// ---------------- maxpool 3x3 stride 2 VALID + mask pool, bf16x8 ----------------
template<int C>
__global__ void maxpool_k(const bf16* __restrict__ in, const float* __restrict__ min_,
                          bf16* __restrict__ out, float* __restrict__ mout,
                          int B, int H, int W, int OH, int OW) {
    long i8 = (long)blockIdx.x * 256 + threadIdx.x;
    long total8 = (long)B * OH * OW * C / 8;
    if (i8 >= total8) return;
    long e0 = i8 * 8;
    int c0 = (int)(e0 % C);
    long osite = e0 / C;
    int ow = (int)(osite % OW); long t2 = osite / OW; int oh = (int)(t2 % OH); long b = t2 / OH;
    float mm = 0.f, p[8];
#pragma unroll
    for (int i = 0; i < 8; i++) p[i] = -1e30f;
    for (int kh = 0; kh < 3; kh++)
    for (int kw = 0; kw < 3; kw++) {
        int h = oh * 2 + kh, w = ow * 2 + kw;
        long is = ((long)b * H + h) * W + w;
        float mv = min_[is];
        if (mv > 0.f) {
            mm = 1.f;
            float f[8];
            ld8(in + is * C + c0, f);
#pragma unroll
            for (int i = 0; i < 8; i++) p[i] = fmaxf(p[i], f[i]);
        }
    }
    float o[8];
#pragma unroll
    for (int i = 0; i < 8; i++) o[i] = (mm > 0.f) ? p[i] : 0.f;
    st8(out + e0, o);
    if (c0 == 0) mout[osite] = mm;
}

// ---------------- ConvLSTM gates via MFMA: slab B + LDS-staged coalesced writes ----------------
// Block = 32 sites (grid NSITE3/32), 4 waves. All waves cover both 16-site m-tiles;
// wave wv owns channel chunks cc = wv*4+j (64 channels). B-frags are contiguous 1KB
// wave-loads from wbl3[tap][kk][n'=g*256+c][32]. Epilogue stages the LSTM output in
// LDS then writes gout in full 64B lines (kills write-allocate amplification).
__global__ void gates_mfma(const bf16* __restrict__ p2, const bf16* __restrict__ wbl3,
                           const float* __restrict__ bl, const float* __restrict__ m2,
                           bf16* __restrict__ gout) {
    __shared__ bf16 sm[32][256];
    const int tid = threadIdx.x;
    const int wv = tid >> 6;
    const int L  = tid & 63;
    const int q  = L >> 4;
    const int lm = L & 15;
    const long base = (long)blockIdx.x * 32;

    int hh[2], ww[2];
    long siteA[2];
#pragma unroll
    for (int i = 0; i < 2; i++) {
        long s = base + i * 16 + lm;
        siteA[i] = s;
        ww[i] = (int)(s % QW); hh[i] = (int)((s / QW) % QH);
    }

    f4v acc[2][4][3];   // [mtile][c-chunk j][gate i/o/g]
#pragma unroll
    for (int i = 0; i < 2; i++)
#pragma unroll
        for (int j = 0; j < 4; j++)
#pragma unroll
            for (int g = 0; g < 3; g++) acc[i][j][g] = (f4v){0.f, 0.f, 0.f, 0.f};

    for (int tap = 0; tap < 9; tap++) {
        const int dh = tap / 3 - 1, dw = tap % 3 - 1;
#pragma unroll
        for (int kk = 0; kk < 4; kk++) {
            s8v a[2];
#pragma unroll
            for (int i = 0; i < 2; i++) {
                int nh = hh[i] + dh, nw = ww[i] + dw;
                bool ok = (nh >= 0) & (nh < QH) & (nw >= 0) & (nw < QW);
                a[i] = (s8v){0, 0, 0, 0, 0, 0, 0, 0};
                if (ok) {
                    long ns = siteA[i] + (long)dh * QW + dw;
                    a[i] = *(const s8v*)(p2 + ns * 128 + kk * 32 + q * 8);
                }
            }
            const bf16* slab = wbl3 + ((long)(tap * 4 + kk)) * 768 * 32 + (long)q * 8;
#pragma unroll
            for (int j = 0; j < 4; j++) {
                int cc = wv * 4 + j;                     // channel chunk 0..15
#pragma unroll
                for (int g = 0; g < 3; g++) {
                    int n = g * 256 + cc * 16 + lm;
                    s8v b = *(const s8v*)(slab + (long)n * 32);
#pragma unroll
                    for (int i = 0; i < 2; i++)
                        acc[i][j][g] = __builtin_amdgcn_mfma_f32_16x16x32_bf16(a[i], b, acc[i][j][g], 0, 0, 0);
                }
            }
        }
    }
    // LSTM epilogue -> LDS (D layout: row=q*4+r, col=lm)
#pragma unroll
    for (int j = 0; j < 4; j++) {
        int c = (wv * 4 + j) * 16 + lm;
        float bi = bl[c], bo = bl[512 + c], bg = bl[768 + c];
#pragma unroll
        for (int i = 0; i < 2; i++) {
#pragma unroll
            for (int r = 0; r < 4; r++) {
                int srow = i * 16 + q * 4 + r;
                float m = m2[base + srow];
                float val = 0.f;
                if (m > 0.f) {
                    float iv = acc[i][j][0][r] + bi;
                    float ov = acc[i][j][1][r] + bo;
                    float gv = acc[i][j][2][r] + bg;
                    float ct = sigmoidf_(iv) * tanhf(gv);
                    val = sigmoidf_(ov) * tanhf(ct);
                }
                sm[srow][c] = f2b(val);
            }
        }
    }
    __syncthreads();
    // coalesced copy LDS -> gout: 16 KB as 4 x (256 thr x 16 B) contiguous chunks
    const uint4* src = (const uint4*)&sm[0][0];
    uint4* dst = (uint4*)(gout + base * 256);
#pragma unroll
    for (int k = 0; k < 4; k++) {
        int idx = k * 256 + tid;
        dst[idx] = src[idx];
    }
}

// ---------------- FC1 via MFMA ----------------
__global__ void fc1_mfma(const bf16* __restrict__ A, const bf16* __restrict__ Wt,
                         const float* __restrict__ lb1, bf16* __restrict__ y1) {
    const int tid = threadIdx.x;
    const int wv = tid >> 6;
    const int L  = tid & 63;
    const int q  = L >> 4, lm = L & 15;
    const int wm = wv >> 1, wn = wv & 1;
    const int bm = blockIdx.x & 31;
    const int bn = blockIdx.x >> 5;
    const int m0 = bm * 64 + wm * 32;
    const int n0 = bn * 64 + wn * 32;

    f4v acc[2][2];
#pragma unroll
    for (int i = 0; i < 2; i++)
#pragma unroll
        for (int j = 0; j < 2; j++) acc[i][j] = (f4v){0.f, 0.f, 0.f, 0.f};

    const bf16* a0p = A  + (long)(m0 + lm) * 8960 + q * 8;
    const bf16* a1p = a0p + (long)16 * 8960;
    const bf16* b0p = Wt + (long)(n0 + lm) * 8960 + q * 8;
    const bf16* b1p = b0p + (long)16 * 8960;

#pragma unroll 2
    for (int k0 = 0; k0 < 8960; k0 += 32) {
        s8v a0 = *(const s8v*)(a0p + k0);
        s8v a1 = *(const s8v*)(a1p + k0);
        s8v b0 = *(const s8v*)(b0p + k0);
        s8v b1 = *(const s8v*)(b1p + k0);
        acc[0][0] = __builtin_amdgcn_mfma_f32_16x16x32_bf16(a0, b0, acc[0][0], 0, 0, 0);
        acc[0][1] = __builtin_amdgcn_mfma_f32_16x16x32_bf16(a0, b1, acc[0][1], 0, 0, 0);
        acc[1][0] = __builtin_amdgcn_mfma_f32_16x16x32_bf16(a1, b0, acc[1][0], 0, 0, 0);
        acc[1][1] = __builtin_amdgcn_mfma_f32_16x16x32_bf16(a1, b1, acc[1][1], 0, 0, 0);
    }
#pragma unroll
    for (int i = 0; i < 2; i++) {
#pragma unroll
        for (int j = 0; j < 2; j++) {
            int nn = n0 + j * 16 + lm;
            float bias = lb1[nn];
#pragma unroll
            for (int r = 0; r < 4; r++) {
                int mm = m0 + i * 16 + q * 4 + r;
                y1[(long)mm * 1024 + nn] = f2b(fmaxf(acc[i][j][r] + bias, 0.f));
            }
        }
    }
}

// ---------------- FC2 ----------------
__global__ void fc2_k(const bf16* __restrict__ y1, const float* __restrict__ lw2,
                      const float* __restrict__ lb2, float* __restrict__ out) {
    long idx = (long)blockIdx.x * 256 + threadIdx.x;
    long total = (long)BB * 420;
    if (idx >= total) return;
    int j = (int)(idx % 420); long b = idx / 420;
    float acc = lb2[j];
    const bf16* yr = y1 + b * 1024;
    for (int k8 = 0; k8 < 1024; k8 += 8) {
        float f[8];
        ld8(yr + k8, f);
#pragma unroll
        for (int i = 0; i < 8; i++) acc += f[i] * lw2[(long)(k8 + i) * 420 + j];
    }
    out[idx] = acc;
}

// ---------------- launch ----------------
extern "C" void kernel_launch(void* const* d_in, const int* in_sizes, int n_in,
                              void* d_out, int out_size, void* d_ws, size_t ws_size,
                              hipStream_t stream) {
    const float* x    = (const float*)d_in[0];
    const int*   mask = (const int*)d_in[1];
    const float* W1 = (const float*)d_in[2];
    const float* g1 = (const float*)d_in[3];
    const float* b1 = (const float*)d_in[4];
    const float* W2 = (const float*)d_in[5];
    const float* g2 = (const float*)d_in[6];
    const float* b2 = (const float*)d_in[7];
    const float* W3 = (const float*)d_in[8];
    const float* g3 = (const float*)d_in[9];
    const float* b3 = (const float*)d_in[10];
    const float* W4 = (const float*)d_in[11];
    const float* g4 = (const float*)d_in[12];
    const float* b4 = (const float*)d_in[13];
    const float* Wl = (const float*)d_in[14];
    const float* bl = (const float*)d_in[15];
    const float* lw1 = (const float*)d_in[16];
    const float* lb1 = (const float*)d_in[17];
    const float* lw2 = (const float*)d_in[18];
    const float* lb2 = (const float*)d_in[19];
    float* out = (float*)d_out;

    float* ws = (float*)d_ws;
    float* m0 = ws + OFF_M0;
    float* m1 = ws + OFF_M1;
    float* m2 = ws + OFF_M2;
    bf16* bufA = (bf16*)(ws + OFF_BF);
    bf16* bufB = bufA + SZ_A;

    bf16* c1   = bufA;            // [NSITE1,16]
    bf16* xm   = bufB;            // [NSITE1,2]  (dead after conv1)
    bf16* c2   = bufB;            // [NSITE1,32]
    bf16* p1   = bufA;            // [NSITE2,32]
    bf16* c3   = bufB;            // [NSITE2,64]
    bf16* c4   = bufA;            // [NSITE2,128]
    bf16* p2   = bufB;            // [NSITE3,128]
    bf16* gout = bufA;            // [NSITE3,256] == A[2048][8960]
    bf16* y1   = bufB;            // [2048,1024]
    bf16* wb2  = bufA + WB2_A;
    bf16* wb3  = bufB + WB3_B;
    bf16* wb4  = bufB + WB4_B;
    bf16* wbl3 = bufA + WBL_A;
    bf16* wfc1 = bufB + WFC1_B;

    hipMemsetAsync(ws, 0, 4096, stream);   // BN stat accumulators

    prep_k<<<(int)((NSITE1 + 255) / 256), 256, 0, stream>>>(x, mask, m0, xm);
    cvt_w_k<<<(9216 + 255) / 256, 256, 0, stream>>>(W2, wb2, 16, 32, 32, 9216);

    conv1_k<<<(int)((NSITE1 + 255) / 256), 256, 0, stream>>>(xm, W1, m0, c1);
    bn_stats<16><<<1280, 256, 0, stream>>>(c1, m0, ws + OFF_S1, ws + OFF_Q1, ws + OFF_N1, NSITE1);
    bn_param<16><<<1, 16, 0, stream>>>(ws + OFF_S1, ws + OFF_Q1, ws + OFF_N1, g1, b1, ws + OFF_SC1, ws + OFF_SH1);
    bn_apply<16><<<(int)(NSITE1 * 16 / 8 / 256), 256, 0, stream>>>(c1, m0, ws + OFF_SC1, ws + OFF_SH1, NSITE1);

    conv_mfma<16, 32, 32, 1, 2, 1, IH, IW><<<(int)(NSITE1 / 64), 256, 0, stream>>>(c1, wb2, m0, c2);
    bn_stats<32><<<1280, 256, 0, stream>>>(c2, m0, ws + OFF_S2, ws + OFF_Q2, nullptr, NSITE1);
    bn_param<32><<<1, 32, 0, stream>>>(ws + OFF_S2, ws + OFF_Q2, ws + OFF_N1, g2, b2, ws + OFF_SC2, ws + OFF_SH2);
    bn_apply<32><<<(int)(NSITE1 * 32 / 8 / 256), 256, 0, stream>>>(c2, m0, ws + OFF_SC2, ws + OFF_SH2, NSITE1);

    maxpool_k<32><<<(int)(NSITE2 * 32 / 8 / 256), 256, 0, stream>>>(c2, m0, p1, m1, BB, IH, IW, PH, PW);

    // c2 (bufB) dead: convert wb3, wb4, wfc1 into bufB slack
    cvt_w_k<<<(18432 + 255) / 256, 256, 0, stream>>>(W3, wb3, 32, 32, 64, 18432);
    cvt_w_k<<<(73728 + 255) / 256, 256, 0, stream>>>(W4, wb4, 64, 64, 128, 73728);
    cvt_fc1_k<<<(int)((9175040L + 255) / 256), 256, 0, stream>>>(lw1, wfc1);

    conv_mfma<32, 32, 64, 1, 4, 1, PH, PW><<<(int)(NSITE2 / 64), 256, 0, stream>>>(p1, wb3, m1, c3);
    bn_stats<64><<<1280, 256, 0, stream>>>(c3, m1, ws + OFF_S3, ws + OFF_Q3, ws + OFF_N2, NSITE2);
    bn_param<64><<<1, 64, 0, stream>>>(ws + OFF_S3, ws + OFF_Q3, ws + OFF_N2, g3, b3, ws + OFF_SC3, ws + OFF_SH3);
    bn_apply<64><<<(int)(NSITE2 * 64 / 8 / 256), 256, 0, stream>>>(c3, m1, ws + OFF_SC3, ws + OFF_SH3, NSITE2);

    conv_mfma<64, 64, 128, 2, 4, 2, PH, PW><<<(int)(NSITE2 / 64), 256, 0, stream>>>(c3, wb4, m1, c4);
    bn_stats<128><<<1280, 256, 0, stream>>>(c4, m1, ws + OFF_S4, ws + OFF_Q4, nullptr, NSITE2);
    bn_param<128><<<1, 128, 0, stream>>>(ws + OFF_S4, ws + OFF_Q4, ws + OFF_N2, g4, b4, ws + OFF_SC4, ws + OFF_SH4);
    bn_apply<128><<<(int)(NSITE2 * 128 / 8 / 256), 256, 0, stream>>>(c4, m1, ws + OFF_SC4, ws + OFF_SH4, NSITE2);

    maxpool_k<128><<<(int)(NSITE3 * 128 / 8 / 256), 256, 0, stream>>>(c4, m1, p2, m2, BB, PH, PW, QH, QW);

    // c4 (bufA) dead: convert wbl3 into bufA past gout's end
    cvt_wl3_k<<<(884736 + 255) / 256, 256, 0, stream>>>(Wl, wbl3);

    gates_mfma<<<(int)(NSITE3 / 32), 256, 0, stream>>>(p2, wbl3, bl, m2, gout);

    fc1_mfma<<<512, 256, 0, stream>>>(gout, wfc1, lb1, y1);

    fc2_k<<<(int)((BB * 420L + 255) / 256), 256, 0, stream>>>(y1, lw2, lb2, out);
}

// Round 7
// 1942.030 us; speedup vs baseline: 1.3216x; 1.1222x over previous
//
#include <hip/hip_runtime.h>
#include <hip/hip_bf16.h>
#include <math.h>

using bf16 = __hip_bfloat16;

typedef short s8v __attribute__((ext_vector_type(8)));   // 8 bf16 bit-pattern (4 VGPRs)
typedef float f4v __attribute__((ext_vector_type(4)));   // MFMA accumulator

// ---------------- problem dims ----------------
static constexpr int  BB  = 2048;
static constexpr int  IH  = 23, IW = 31;   // stage 1 spatial
static constexpr int  PH  = 11, PW = 15;   // after pool1
static constexpr int  QH  = 5,  QW = 7;    // after pool2
static constexpr long NSITE1 = (long)BB * IH * IW;   // 1,460,224 = 64*22,816
static constexpr long NSITE2 = (long)BB * PH * PW;   //   337,920 = 64*5,280
static constexpr long NSITE3 = (long)BB * QH * QW;   //    71,680 = 32*2,240

// ---------------- workspace layout (same total as round 1: 187,449,344 B) ----------------
static constexpr long OFF_S1 = 0,   OFF_Q1 = 64;
static constexpr long OFF_S2 = 128, OFF_Q2 = 192;
static constexpr long OFF_S3 = 256, OFF_Q3 = 320;
static constexpr long OFF_S4 = 384, OFF_Q4 = 512;
static constexpr long OFF_N1 = 640, OFF_N2 = 641;
static constexpr long OFF_SC1 = 704,  OFF_SH1 = 768;
static constexpr long OFF_SC2 = 832,  OFF_SH2 = 896;
static constexpr long OFF_SC3 = 960,  OFF_SH3 = 1024;
static constexpr long OFF_SC4 = 1088, OFF_SH4 = 1216;
static constexpr long OFF_M0 = 2048;
static constexpr long OFF_M1 = OFF_M0 + NSITE1;
static constexpr long OFF_M2 = OFF_M1 + NSITE2;
static constexpr long OFF_BF = 1871872;             // float offset where bf16 area starts
static constexpr long SZ_A   = 43253760L;           // bf16 elems per region
// bf16 weight stashes carved from dead phases of bufA/bufB (see launch ordering):
static constexpr long WB2_A  = 25000000L;  // [9][32][32]  = 9,216   (bufA past c1)
static constexpr long WB3_B  = 22000000L;  // [9][64][32]  = 18,432  (bufB past c3)
static constexpr long WB4_B  = 22100000L;  // [9][128][64] = 73,728  (bufB past c3)
static constexpr long WBL_A  = 20000000L;  // [9][4][768][32] = 884,736 (bufA past gout)
static constexpr long WFC1_B = 23000000L;  // [1024][8960] = 9,175,040 (bufB, live pool1->fc1)

__device__ __forceinline__ float sigmoidf_(float x) { return 1.f / (1.f + __expf(-x)); }
__device__ __forceinline__ float b2f(bf16 v) { return __bfloat162float(v); }
__device__ __forceinline__ bf16  f2b(float v) { return __float2bfloat16(v); }

// load 8 consecutive bf16 (16B aligned) -> 8 floats
__device__ __forceinline__ void ld8(const bf16* p, float* f) {
    union { uint4 u; unsigned short s[8]; } cv;
    cv.u = *(const uint4*)p;
#pragma unroll
    for (int i = 0; i < 8; i++) f[i] = __uint_as_float(((unsigned int)cv.s[i]) << 16);
}
// store 8 floats -> 8 consecutive bf16 (16B aligned)
__device__ __forceinline__ void st8(bf16* p, const float* f) {
    union { uint4 u; bf16 h[8]; } cv;
#pragma unroll
    for (int i = 0; i < 8; i++) cv.h[i] = f2b(f[i]);
    *(uint4*)p = cv.u;
}

// ---------------- weight convert+transpose: W[tap][cin][cout] f32 -> wb[tap][cout][cinp] bf16 ----------------
__global__ void cvt_w_k(const float* __restrict__ W, bf16* __restrict__ wb,
                        int CIN, int CINP, int COUT, int total) {
    int idx = blockIdx.x * 256 + threadIdx.x;
    if (idx >= total) return;
    int ci  = idx % CINP;
    int t2  = idx / CINP;
    int co  = t2 % COUT;
    int tap = t2 / COUT;
    wb[idx] = (ci < CIN) ? f2b(W[((long)(tap * CIN + ci)) * COUT + co]) : f2b(0.f);
}

// ---------------- LSTM weight: Wl[tap][cin][1024] f32 -> wbl3[tap][kk][n'=g*256+c][32] bf16 ----------------
// g: 0->i (col c), 1->o (col 512+c), 2->g (col 768+c). f-gate (col 256+c) dropped (c0=0).
__global__ void cvt_wl3_k(const float* __restrict__ Wl, bf16* __restrict__ wbl3) {
    int idx = blockIdx.x * 256 + threadIdx.x;
    if (idx >= 884736) return;
    int kidx = idx & 31;
    int n    = (idx >> 5) % 768;
    int kk   = (idx >> 5) / 768 % 4;
    int tap  = idx / (32 * 768 * 4);
    int g = n >> 8, c = n & 255;
    int col = (g == 0) ? c : (g == 1 ? 512 + c : 768 + c);
    int cin = kk * 32 + kidx;
    wbl3[idx] = f2b(Wl[((long)(tap * 128 + cin)) * 1024 + col]);
}

// ---------------- FC1 weight: lw1[k=c*35+hw][j] f32 -> wfc1[j][k'=hw*256+c] bf16 ----------------
__global__ void cvt_fc1_k(const float* __restrict__ lw1, bf16* __restrict__ wfc1) {
    long idx = (long)blockIdx.x * 256 + threadIdx.x;
    if (idx >= 9175040L) return;
    int c  = (int)(idx & 255);
    int hw = (int)((idx >> 8) % 35);
    int j  = (int)(idx / 8960);
    wfc1[idx] = f2b(lw1[(long)(c * 35 + hw) * 1024 + j]);
}

// ---------------- prep: int mask -> float, xm = bf16(x*m) ----------------
__global__ void prep_k(const float* __restrict__ x, const int* __restrict__ mask,
                       float* __restrict__ m0, bf16* __restrict__ xm) {
    long idx = (long)blockIdx.x * 256 + threadIdx.x;
    if (idx >= NSITE1) return;
    float m = (mask[idx] != 0) ? 1.f : 0.f;
    m0[idx] = m;
    xm[idx * 2 + 0] = f2b(x[idx * 2 + 0] * m);
    xm[idx * 2 + 1] = f2b(x[idx * 2 + 1] * m);
}

// ---------------- conv1: 2->16, one site per thread (uniform weight loads) ----------------
__global__ void conv1_k(const bf16* __restrict__ xm, const float* __restrict__ Wt,
                        const float* __restrict__ m0, bf16* __restrict__ out) {
    const int H = IH, W = IW;
    long site = (long)blockIdx.x * 256 + threadIdx.x;
    if (site >= NSITE1) return;
    float acc[16];
#pragma unroll
    for (int i = 0; i < 16; i++) acc[i] = 0.f;
    float mk = m0[site];
    if (mk > 0.f) {
        int w = (int)(site % W); int h = (int)((site / W) % H);
        for (int tap = 0; tap < 9; tap++) {
            int dh = tap / 3 - 1, dw = tap % 3 - 1;
            int nh = h + dh, nw = w + dw;
            if (nh < 0 || nh >= H || nw < 0 || nw >= W) continue;
            long ns = site + (long)dh * W + dw;
            float i0 = b2f(xm[ns * 2 + 0]), i1 = b2f(xm[ns * 2 + 1]);
            const float* wp = Wt + tap * 32;   // [2][16]
#pragma unroll
            for (int co = 0; co < 16; co++) acc[co] += i0 * wp[co] + i1 * wp[16 + co];
        }
    }
    st8(out + site * 16, acc);
    st8(out + site * 16 + 8, acc + 8);
}

// ---------------- MFMA direct conv 3x3 SAME ----------------
template<int CIN, int CINP, int COUT, int KK, int MT_W, int NT_W, int H, int W>
__global__ void conv_mfma(const bf16* __restrict__ in, const bf16* __restrict__ wb,
                          const float* __restrict__ mask, bf16* __restrict__ out) {
    constexpr int NT = COUT / 16;
    constexpr int NWN = NT / NT_W;            // waves along N
    const int tid = threadIdx.x;
    const int wv = tid >> 6;
    const int L  = tid & 63;
    const int q  = (L >> 4);                  // quad
    const int lm = L & 15;
    const int wn = wv % NWN;
    const int wm = wv / NWN;
    const int mt0 = wm * MT_W;
    const long base = (long)blockIdx.x * 64;

    int hh[MT_W], ww[MT_W];
    long siteA[MT_W];
#pragma unroll
    for (int i = 0; i < MT_W; i++) {
        long s = base + (mt0 + i) * 16 + lm;
        siteA[i] = s;
        int wq = (int)(s % W); long t2 = s / W;
        hh[i] = (int)(t2 % H); ww[i] = wq;
    }

    f4v acc[MT_W][NT_W];
#pragma unroll
    for (int i = 0; i < MT_W; i++)
#pragma unroll
        for (int j = 0; j < NT_W; j++) acc[i][j] = (f4v){0.f, 0.f, 0.f, 0.f};

    for (int tap = 0; tap < 9; tap++) {
        const int dh = tap / 3 - 1, dw = tap % 3 - 1;
#pragma unroll
        for (int kk = 0; kk < KK; kk++) {
            s8v a[MT_W];
#pragma unroll
            for (int i = 0; i < MT_W; i++) {
                int nh = hh[i] + dh, nw = ww[i] + dw;
                bool ok = (nh >= 0) & (nh < H) & (nw >= 0) & (nw < W);
                a[i] = (s8v){0, 0, 0, 0, 0, 0, 0, 0};
                if (ok) {
                    long ns = siteA[i] + (long)dh * W + dw;
                    a[i] = *(const s8v*)(in + ns * CIN + kk * 32 + q * 8);
                }
            }
#pragma unroll
            for (int j = 0; j < NT_W; j++) {
                int co = (wn * NT_W + j) * 16 + lm;
                s8v b = *(const s8v*)(wb + ((long)(tap * COUT + co)) * CINP + kk * 32 + q * 8);
#pragma unroll
                for (int i = 0; i < MT_W; i++)
                    acc[i][j] = __builtin_amdgcn_mfma_f32_16x16x32_bf16(a[i], b, acc[i][j], 0, 0, 0);
            }
        }
    }
#pragma unroll
    for (int i = 0; i < MT_W; i++) {
#pragma unroll
        for (int r = 0; r < 4; r++) {
            long so = base + (mt0 + i) * 16 + q * 4 + r;
            float mk = mask[so];
#pragma unroll
            for (int j = 0; j < NT_W; j++) {
                int co = (wn * NT_W + j) * 16 + lm;
                out[so * COUT + co] = f2b(mk > 0.f ? acc[i][j][r] : 0.f);
            }
        }
    }
}

// ---------------- BN stats (bf16x8 vector loads) ----------------
template<int C>
__global__ void bn_stats(const bf16* __restrict__ v, const float* __restrict__ mask,
                         float* __restrict__ sum, float* __restrict__ sumsq,
                         float* __restrict__ count, long nsites) {
    __shared__ float s_sum[C], s_ss[C];
    __shared__ float s_cnt;
    int tid = threadIdx.x;
    if (tid < C) { s_sum[tid] = 0.f; s_ss[tid] = 0.f; }
    if (tid == 0) s_cnt = 0.f;
    __syncthreads();
    const long total8 = nsites * C / 8;
    const long stride = (long)gridDim.x * 256;
    const int c0 = (int)((((long)blockIdx.x * 256 + tid) * 8) % C);  // fixed per thread
    float ls[8], lss[8];
#pragma unroll
    for (int i = 0; i < 8; i++) { ls[i] = 0.f; lss[i] = 0.f; }
    float lc = 0.f;
    for (long e8 = (long)blockIdx.x * 256 + tid; e8 < total8; e8 += stride) {
        long e0 = e8 * 8;
        float f[8];
        ld8(v + e0, f);
#pragma unroll
        for (int i = 0; i < 8; i++) { ls[i] += f[i]; lss[i] += f[i] * f[i]; }
        if (count != nullptr && c0 == 0) lc += (mask[e0 / C] > 0.f) ? 1.f : 0.f;
    }
#pragma unroll
    for (int i = 0; i < 8; i++) {
        atomicAdd(&s_sum[c0 + i], ls[i]);
        atomicAdd(&s_ss[c0 + i], lss[i]);
    }
    if (count != nullptr && c0 == 0) atomicAdd(&s_cnt, lc);
    __syncthreads();
    if (tid < C) { atomicAdd(&sum[tid], s_sum[tid]); atomicAdd(&sumsq[tid], s_ss[tid]); }
    if (count != nullptr && tid == 0) atomicAdd(count, s_cnt);
}

template<int C>
__global__ void bn_param(const float* __restrict__ sum, const float* __restrict__ ss,
                         const float* __restrict__ count,
                         const float* __restrict__ g, const float* __restrict__ b,
                         float* __restrict__ scale, float* __restrict__ shift) {
    int c = threadIdx.x;
    if (c >= C) return;
    float n = fmaxf(count[0], 1.f);
    float mean = sum[c] / n;
    float var  = ss[c] / n - mean * mean;
    float sc = (1.f / sqrtf(var + 1e-4f)) * g[c];
    scale[c] = sc;
    shift[c] = b[c] - mean * sc;
}

// ---------------- BN apply (+ReLU, masked), in-place, bf16x8 ----------------
template<int C>
__global__ void bn_apply(bf16* __restrict__ v, const float* __restrict__ mask,
                         const float* __restrict__ scale, const float* __restrict__ shift,
                         long nsites) {
    long i8 = (long)blockIdx.x * 256 + threadIdx.x;
    if (i8 >= nsites * C / 8) return;
    long e0 = i8 * 8;
    int c0 = (int)(e0 % C);
    long site = e0 / C;
    float mk = mask[site];
    float f[8], o[8];
    ld8(v + e0, f);
#pragma unroll
    for (int i = 0; i < 8; i++)
        o[i] = (mk > 0.f) ? fmaxf(f[i] * scale[c0 + i] + shift[c0 + i], 0.f) : 0.f;
    st8(v + e0, o);
}

// ---------------- maxpool 3x3 stride 2 VALID + mask pool, bf16x8 ----------------
template<int C>
__global__ void maxpool_k(const bf16* __restrict__ in, const float* __restrict__ min_,
                          bf16* __restrict__ out, float* __restrict__ mout,
                          int B, int H, int W, int OH, int OW) {
    long i8 = (long)blockIdx.x * 256 + threadIdx.x;
    long total8 = (long)B * OH * OW * C / 8;
    if (i8 >= total8) return;
    long e0 = i8 * 8;
    int c0 = (int)(e0 % C);
    long osite = e0 / C;
    int ow = (int)(osite % OW); long t2 = osite / OW; int oh = (int)(t2 % OH); long b = t2 / OH;
    float mm = 0.f, p[8];
#pragma unroll
    for (int i = 0; i < 8; i++) p[i] = -1e30f;
    for (int kh = 0; kh < 3; kh++)
    for (int kw = 0; kw < 3; kw++) {
        int h = oh * 2 + kh, w = ow * 2 + kw;
        long is = ((long)b * H + h) * W + w;
        float mv = min_[is];
        if (mv > 0.f) {
            mm = 1.f;
            float f[8];
            ld8(in + is * C + c0, f);
#pragma unroll
            for (int i = 0; i < 8; i++) p[i] = fmaxf(p[i], f[i]);
        }
    }
    float o[8];
#pragma unroll
    for (int i = 0; i < 8; i++) o[i] = (mm > 0.f) ? p[i] : 0.f;
    st8(out + e0, o);
    if (c0 == 0) mout[osite] = mm;
}

// ---------------- ConvLSTM gates via MFMA: slab B + LDS-staged coalesced writes ----------------
// Block = 32 sites (grid NSITE3/32), 4 waves. All waves cover both 16-site m-tiles;
// wave wv owns channel chunks cc = wv*4+j (64 channels). B-frags are contiguous 1KB
// wave-loads from wbl3[tap][kk][n'=g*256+c][32]. Epilogue stages the LSTM output in
// LDS then writes gout in full 64B lines.
// __launch_bounds__(256,2): allow ~256 VGPRs/wave (acc 96 AGPR + batched B-frags)
// so the compiler does NOT cap at 64 VGPR and spill to scratch (R6: 860 MB of
// unexplained HBM traffic = spill R/W; VGPR_Count was 64).
__global__ void __launch_bounds__(256, 2)
gates_mfma(const bf16* __restrict__ p2, const bf16* __restrict__ wbl3,
           const float* __restrict__ bl, const float* __restrict__ m2,
           bf16* __restrict__ gout) {
    __shared__ bf16 sm[32][256];
    const int tid = threadIdx.x;
    const int wv = tid >> 6;
    const int L  = tid & 63;
    const int q  = L >> 4;
    const int lm = L & 15;
    const long base = (long)blockIdx.x * 32;

    int hh[2], ww[2];
    long siteA[2];
#pragma unroll
    for (int i = 0; i < 2; i++) {
        long s = base + i * 16 + lm;
        siteA[i] = s;
        ww[i] = (int)(s % QW); hh[i] = (int)((s / QW) % QH);
    }

    f4v acc[2][4][3];   // [mtile][c-chunk j][gate i/o/g]
#pragma unroll
    for (int i = 0; i < 2; i++)
#pragma unroll
        for (int j = 0; j < 4; j++)
#pragma unroll
            for (int g = 0; g < 3; g++) acc[i][j][g] = (f4v){0.f, 0.f, 0.f, 0.f};

    for (int tap = 0; tap < 9; tap++) {
        const int dh = tap / 3 - 1, dw = tap % 3 - 1;
#pragma unroll
        for (int kk = 0; kk < 4; kk++) {
            s8v a[2];
#pragma unroll
            for (int i = 0; i < 2; i++) {
                int nh = hh[i] + dh, nw = ww[i] + dw;
                bool ok = (nh >= 0) & (nh < QH) & (nw >= 0) & (nw < QW);
                a[i] = (s8v){0, 0, 0, 0, 0, 0, 0, 0};
                if (ok) {
                    long ns = siteA[i] + (long)dh * QW + dw;
                    a[i] = *(const s8v*)(p2 + ns * 128 + kk * 32 + q * 8);
                }
            }
            const bf16* slab = wbl3 + ((long)(tap * 4 + kk)) * 768 * 32 + (long)q * 8;
#pragma unroll
            for (int j = 0; j < 4; j++) {
                int cc = wv * 4 + j;                     // channel chunk 0..15
#pragma unroll
                for (int g = 0; g < 3; g++) {
                    int n = g * 256 + cc * 16 + lm;
                    s8v b = *(const s8v*)(slab + (long)n * 32);
#pragma unroll
                    for (int i = 0; i < 2; i++)
                        acc[i][j][g] = __builtin_amdgcn_mfma_f32_16x16x32_bf16(a[i], b, acc[i][j][g], 0, 0, 0);
                }
            }
        }
    }
    // LSTM epilogue -> LDS (D layout: row=q*4+r, col=lm)
#pragma unroll
    for (int j = 0; j < 4; j++) {
        int c = (wv * 4 + j) * 16 + lm;
        float bi = bl[c], bo = bl[512 + c], bg = bl[768 + c];
#pragma unroll
        for (int i = 0; i < 2; i++) {
#pragma unroll
            for (int r = 0; r < 4; r++) {
                int srow = i * 16 + q * 4 + r;
                float m = m2[base + srow];
                float val = 0.f;
                if (m > 0.f) {
                    float iv = acc[i][j][0][r] + bi;
                    float ov = acc[i][j][1][r] + bo;
                    float gv = acc[i][j][2][r] + bg;
                    float ct = sigmoidf_(iv) * tanhf(gv);
                    val = sigmoidf_(ov) * tanhf(ct);
                }
                sm[srow][c] = f2b(val);
            }
        }
    }
    __syncthreads();
    // coalesced copy LDS -> gout: 16 KB as 4 x (256 thr x 16 B) contiguous chunks
    const uint4* src = (const uint4*)&sm[0][0];
    uint4* dst = (uint4*)(gout + base * 256);
#pragma unroll
    for (int k = 0; k < 4; k++) {
        int idx = k * 256 + tid;
        dst[idx] = src[idx];
    }
}

// ---------------- FC1 via MFMA ----------------
__global__ void fc1_mfma(const bf16* __restrict__ A, const bf16* __restrict__ Wt,
                         const float* __restrict__ lb1, bf16* __restrict__ y1) {
    const int tid = threadIdx.x;
    const int wv = tid >> 6;
    const int L  = tid & 63;
    const int q  = L >> 4, lm = L & 15;
    const int wm = wv >> 1, wn = wv & 1;
    const int bm = blockIdx.x & 31;
    const int bn = blockIdx.x >> 5;
    const int m0 = bm * 64 + wm * 32;
    const int n0 = bn * 64 + wn * 32;

    f4v acc[2][2];
#pragma unroll
    for (int i = 0; i < 2; i++)
#pragma unroll
        for (int j = 0; j < 2; j++) acc[i][j] = (f4v){0.f, 0.f, 0.f, 0.f};

    const bf16* a0p = A  + (long)(m0 + lm) * 8960 + q * 8;
    const bf16* a1p = a0p + (long)16 * 8960;
    const bf16* b0p = Wt + (long)(n0 + lm) * 8960 + q * 8;
    const bf16* b1p = b0p + (long)16 * 8960;

#pragma unroll 2
    for (int k0 = 0; k0 < 8960; k0 += 32) {
        s8v a0 = *(const s8v*)(a0p + k0);
        s8v a1 = *(const s8v*)(a1p + k0);
        s8v b0 = *(const s8v*)(b0p + k0);
        s8v b1 = *(const s8v*)(b1p + k0);
        acc[0][0] = __builtin_amdgcn_mfma_f32_16x16x32_bf16(a0, b0, acc[0][0], 0, 0, 0);
        acc[0][1] = __builtin_amdgcn_mfma_f32_16x16x32_bf16(a0, b1, acc[0][1], 0, 0, 0);
        acc[1][0] = __builtin_amdgcn_mfma_f32_16x16x32_bf16(a1, b0, acc[1][0], 0, 0, 0);
        acc[1][1] = __builtin_amdgcn_mfma_f32_16x16x32_bf16(a1, b1, acc[1][1], 0, 0, 0);
    }
#pragma unroll
    for (int i = 0; i < 2; i++) {
#pragma unroll
        for (int j = 0; j < 2; j++) {
            int nn = n0 + j * 16 + lm;
            float bias = lb1[nn];
#pragma unroll
            for (int r = 0; r < 4; r++) {
                int mm = m0 + i * 16 + q * 4 + r;
                y1[(long)mm * 1024 + nn] = f2b(fmaxf(acc[i][j][r] + bias, 0.f));
            }
        }
    }
}

// ---------------- FC2 ----------------
__global__ void fc2_k(const bf16* __restrict__ y1, const float* __restrict__ lw2,
                      const float* __restrict__ lb2, float* __restrict__ out) {
    long idx = (long)blockIdx.x * 256 + threadIdx.x;
    long total = (long)BB * 420;
    if (idx >= total) return;
    int j = (int)(idx % 420); long b = idx / 420;
    float acc = lb2[j];
    const bf16* yr = y1 + b * 1024;
    for (int k8 = 0; k8 < 1024; k8 += 8) {
        float f[8];
        ld8(yr + k8, f);
#pragma unroll
        for (int i = 0; i < 8; i++) acc += f[i] * lw2[(long)(k8 + i) * 420 + j];
    }
    out[idx] = acc;
}

// ---------------- launch ----------------
extern "C" void kernel_launch(void* const* d_in, const int* in_sizes, int n_in,
                              void* d_out, int out_size, void* d_ws, size_t ws_size,
                              hipStream_t stream) {
    const float* x    = (const float*)d_in[0];
    const int*   mask = (const int*)d_in[1];
    const float* W1 = (const float*)d_in[2];
    const float* g1 = (const float*)d_in[3];
    const float* b1 = (const float*)d_in[4];
    const float* W2 = (const float*)d_in[5];
    const float* g2 = (const float*)d_in[6];
    const float* b2 = (const float*)d_in[7];
    const float* W3 = (const float*)d_in[8];
    const float* g3 = (const float*)d_in[9];
    const float* b3 = (const float*)d_in[10];
    const float* W4 = (const float*)d_in[11];
    const float* g4 = (const float*)d_in[12];
    const float* b4 = (const float*)d_in[13];
    const float* Wl = (const float*)d_in[14];
    const float* bl = (const float*)d_in[15];
    const float* lw1 = (const float*)d_in[16];
    const float* lb1 = (const float*)d_in[17];
    const float* lw2 = (const float*)d_in[18];
    const float* lb2 = (const float*)d_in[19];
    float* out = (float*)d_out;

    float* ws = (float*)d_ws;
    float* m0 = ws + OFF_M0;
    float* m1 = ws + OFF_M1;
    float* m2 = ws + OFF_M2;
    bf16* bufA = (bf16*)(ws + OFF_BF);
    bf16* bufB = bufA + SZ_A;

    bf16* c1   = bufA;            // [NSITE1,16]
    bf16* xm   = bufB;            // [NSITE1,2]  (dead after conv1)
    bf16* c2   = bufB;            // [NSITE1,32]
    bf16* p1   = bufA;            // [NSITE2,32]
    bf16* c3   = bufB;            // [NSITE2,64]
    bf16* c4   = bufA;            // [NSITE2,128]
    bf16* p2   = bufB;            // [NSITE3,128]
    bf16* gout = bufA;            // [NSITE3,256] == A[2048][8960]
    bf16* y1   = bufB;            // [2048,1024]
    bf16* wb2  = bufA + WB2_A;
    bf16* wb3  = bufB + WB3_B;
    bf16* wb4  = bufB + WB4_B;
    bf16* wbl3 = bufA + WBL_A;
    bf16* wfc1 = bufB + WFC1_B;

    hipMemsetAsync(ws, 0, 4096, stream);   // BN stat accumulators

    prep_k<<<(int)((NSITE1 + 255) / 256), 256, 0, stream>>>(x, mask, m0, xm);
    cvt_w_k<<<(9216 + 255) / 256, 256, 0, stream>>>(W2, wb2, 16, 32, 32, 9216);

    conv1_k<<<(int)((NSITE1 + 255) / 256), 256, 0, stream>>>(xm, W1, m0, c1);
    bn_stats<16><<<1280, 256, 0, stream>>>(c1, m0, ws + OFF_S1, ws + OFF_Q1, ws + OFF_N1, NSITE1);
    bn_param<16><<<1, 16, 0, stream>>>(ws + OFF_S1, ws + OFF_Q1, ws + OFF_N1, g1, b1, ws + OFF_SC1, ws + OFF_SH1);
    bn_apply<16><<<(int)(NSITE1 * 16 / 8 / 256), 256, 0, stream>>>(c1, m0, ws + OFF_SC1, ws + OFF_SH1, NSITE1);

    conv_mfma<16, 32, 32, 1, 2, 1, IH, IW><<<(int)(NSITE1 / 64), 256, 0, stream>>>(c1, wb2, m0, c2);
    bn_stats<32><<<1280, 256, 0, stream>>>(c2, m0, ws + OFF_S2, ws + OFF_Q2, nullptr, NSITE1);
    bn_param<32><<<1, 32, 0, stream>>>(ws + OFF_S2, ws + OFF_Q2, ws + OFF_N1, g2, b2, ws + OFF_SC2, ws + OFF_SH2);
    bn_apply<32><<<(int)(NSITE1 * 32 / 8 / 256), 256, 0, stream>>>(c2, m0, ws + OFF_SC2, ws + OFF_SH2, NSITE1);

    maxpool_k<32><<<(int)(NSITE2 * 32 / 8 / 256), 256, 0, stream>>>(c2, m0, p1, m1, BB, IH, IW, PH, PW);

    // c2 (bufB) dead: convert wb3, wb4, wfc1 into bufB slack
    cvt_w_k<<<(18432 + 255) / 256, 256, 0, stream>>>(W3, wb3, 32, 32, 64, 18432);
    cvt_w_k<<<(73728 + 255) / 256, 256, 0, stream>>>(W4, wb4, 64, 64, 128, 73728);
    cvt_fc1_k<<<(int)((9175040L + 255) / 256), 256, 0, stream>>>(lw1, wfc1);

    conv_mfma<32, 32, 64, 1, 4, 1, PH, PW><<<(int)(NSITE2 / 64), 256, 0, stream>>>(p1, wb3, m1, c3);
    bn_stats<64><<<1280, 256, 0, stream>>>(c3, m1, ws + OFF_S3, ws + OFF_Q3, ws + OFF_N2, NSITE2);
    bn_param<64><<<1, 64, 0, stream>>>(ws + OFF_S3, ws + OFF_Q3, ws + OFF_N2, g3, b3, ws + OFF_SC3, ws + OFF_SH3);
    bn_apply<64><<<(int)(NSITE2 * 64 / 8 / 256), 256, 0, stream>>>(c3, m1, ws + OFF_SC3, ws + OFF_SH3, NSITE2);

    conv_mfma<64, 64, 128, 2, 4, 2, PH, PW><<<(int)(NSITE2 / 64), 256, 0, stream>>>(c3, wb4, m1, c4);
    bn_stats<128><<<1280, 256, 0, stream>>>(c4, m1, ws + OFF_S4, ws + OFF_Q4, nullptr, NSITE2);
    bn_param<128><<<1, 128, 0, stream>>>(ws + OFF_S4, ws + OFF_Q4, ws + OFF_N2, g4, b4, ws + OFF_SC4, ws + OFF_SH4);
    bn_apply<128><<<(int)(NSITE2 * 128 / 8 / 256), 256, 0, stream>>>(c4, m1, ws + OFF_SC4, ws + OFF_SH4, NSITE2);

    maxpool_k<128><<<(int)(NSITE3 * 128 / 8 / 256), 256, 0, stream>>>(c4, m1, p2, m2, BB, PH, PW, QH, QW);

    // c4 (bufA) dead: convert wbl3 into bufA past gout's end
    cvt_wl3_k<<<(884736 + 255) / 256, 256, 0, stream>>>(Wl, wbl3);

    gates_mfma<<<(int)(NSITE3 / 32), 256, 0, stream>>>(p2, wbl3, bl, m2, gout);

    fc1_mfma<<<512, 256, 0, stream>>>(gout, wfc1, lb1, y1);

    fc2_k<<<(int)((BB * 420L + 255) / 256), 256, 0, stream>>>(y1, lw2, lb2, out);
}

// Round 8
// 1517.631 us; speedup vs baseline: 1.6912x; 1.2796x over previous
//
#include <hip/hip_runtime.h>
#include <hip/hip_bf16.h>
#include <math.h>

using bf16 = __hip_bfloat16;

typedef short s8v __attribute__((ext_vector_type(8)));   // 8 bf16 bit-pattern (4 VGPRs)
typedef float f4v __attribute__((ext_vector_type(4)));   // MFMA accumulator

// ---------------- problem dims ----------------
static constexpr int  BB  = 2048;
static constexpr int  IH  = 23, IW = 31;   // stage 1 spatial
static constexpr int  PH  = 11, PW = 15;   // after pool1
static constexpr int  QH  = 5,  QW = 7;    // after pool2
static constexpr long NSITE1 = (long)BB * IH * IW;   // 1,460,224
static constexpr long NSITE2 = (long)BB * PH * PW;   //   337,920
static constexpr long NSITE3 = (long)BB * QH * QW;   //    71,680

// ---------------- workspace layout ----------------
static constexpr long OFF_S1 = 0,   OFF_Q1 = 64;
static constexpr long OFF_S2 = 128, OFF_Q2 = 192;
static constexpr long OFF_S3 = 256, OFF_Q3 = 320;
static constexpr long OFF_S4 = 384, OFF_Q4 = 512;
static constexpr long OFF_N1 = 640, OFF_N2 = 641;
static constexpr long OFF_SC1 = 704,  OFF_SH1 = 768;
static constexpr long OFF_SC2 = 832,  OFF_SH2 = 896;
static constexpr long OFF_SC3 = 960,  OFF_SH3 = 1024;
static constexpr long OFF_SC4 = 1088, OFF_SH4 = 1216;
static constexpr long OFF_M0 = 2048;
static constexpr long OFF_M1 = OFF_M0 + NSITE1;
static constexpr long OFF_M2 = OFF_M1 + NSITE2;      // m2h: hw-major mask [hw*2048+b]
static constexpr long OFF_BF = 1871872;              // float offset where bf16 area starts
static constexpr long SZ_A   = 43253760L;            // bf16 elems per region
static constexpr long WB2_A  = 25000000L;  // [9][32][32]
static constexpr long WB3_B  = 22000000L;  // [9][64][32]
static constexpr long WB4_B  = 22100000L;  // [9][128][64]
static constexpr long WBL_A  = 20000000L;  // [9][4][768][32] = 884,736
static constexpr long WFC1_B = 23000000L;  // wfc1T8 [1120][1024][8] = 9,175,040

__device__ __forceinline__ float sigmoidf_(float x) { return 1.f / (1.f + __expf(-x)); }
__device__ __forceinline__ float b2f(bf16 v) { return __bfloat162float(v); }
__device__ __forceinline__ bf16  f2b(float v) { return __float2bfloat16(v); }

__device__ __forceinline__ void ld8(const bf16* p, float* f) {
    union { uint4 u; unsigned short s[8]; } cv;
    cv.u = *(const uint4*)p;
#pragma unroll
    for (int i = 0; i < 8; i++) f[i] = __uint_as_float(((unsigned int)cv.s[i]) << 16);
}
__device__ __forceinline__ void st8(bf16* p, const float* f) {
    union { uint4 u; bf16 h[8]; } cv;
#pragma unroll
    for (int i = 0; i < 8; i++) cv.h[i] = f2b(f[i]);
    *(uint4*)p = cv.u;
}

// ---------------- weight convert: W[tap][cin][cout] f32 -> wb[tap][cout][cinp] bf16 ----------------
__global__ void cvt_w_k(const float* __restrict__ W, bf16* __restrict__ wb,
                        int CIN, int CINP, int COUT, int total) {
    int idx = blockIdx.x * 256 + threadIdx.x;
    if (idx >= total) return;
    int ci  = idx % CINP;
    int t2  = idx / CINP;
    int co  = t2 % COUT;
    int tap = t2 / COUT;
    wb[idx] = (ci < CIN) ? f2b(W[((long)(tap * CIN + ci)) * COUT + co]) : f2b(0.f);
}

// ---------------- LSTM weight: Wl[tap][cin][1024] -> wbl3[tap][kk][n'=g*256+c][32] ----------------
__global__ void cvt_wl3_k(const float* __restrict__ Wl, bf16* __restrict__ wbl3) {
    int idx = blockIdx.x * 256 + threadIdx.x;
    if (idx >= 884736) return;
    int kidx = idx & 31;
    int n    = (idx >> 5) % 768;
    int kk   = (idx >> 5) / 768 % 4;
    int tap  = idx / (32 * 768 * 4);
    int g = n >> 8, c = n & 255;
    int col = (g == 0) ? c : (g == 1 ? 512 + c : 768 + c);
    int cin = kk * 32 + kidx;
    wbl3[idx] = f2b(Wl[((long)(tap * 128 + cin)) * 1024 + col]);
}

// ---------------- FC1 weight: lw1[k=c*35+hw][j] f32 -> wfc1T8[k8g=hw*32+c8][j][8] bf16 ----------------
__global__ void cvt_fc1T8_k(const float* __restrict__ lw1, bf16* __restrict__ wfc1) {
    int t = blockIdx.x * 256 + threadIdx.x;          // 1120*1024 threads
    if (t >= 1146880) return;
    int j   = t & 1023;
    int k8g = t >> 10;
    int hw  = k8g >> 5;
    int c8  = k8g & 31;
    float f[8];
#pragma unroll
    for (int c7 = 0; c7 < 8; c7++)
        f[c7] = lw1[((long)((c8 * 8 + c7) * 35 + hw)) * 1024 + j];
    st8(wfc1 + (long)t * 8, f);
}

// ---------------- prep ----------------
__global__ void prep_k(const float* __restrict__ x, const int* __restrict__ mask,
                       float* __restrict__ m0, bf16* __restrict__ xm) {
    long idx = (long)blockIdx.x * 256 + threadIdx.x;
    if (idx >= NSITE1) return;
    float m = (mask[idx] != 0) ? 1.f : 0.f;
    m0[idx] = m;
    xm[idx * 2 + 0] = f2b(x[idx * 2 + 0] * m);
    xm[idx * 2 + 1] = f2b(x[idx * 2 + 1] * m);
}

// ---------------- conv1: 2->16 ----------------
__global__ void conv1_k(const bf16* __restrict__ xm, const float* __restrict__ Wt,
                        const float* __restrict__ m0, bf16* __restrict__ out) {
    const int H = IH, W = IW;
    long site = (long)blockIdx.x * 256 + threadIdx.x;
    if (site >= NSITE1) return;
    float acc[16];
#pragma unroll
    for (int i = 0; i < 16; i++) acc[i] = 0.f;
    float mk = m0[site];
    if (mk > 0.f) {
        int w = (int)(site % W); int h = (int)((site / W) % H);
        for (int tap = 0; tap < 9; tap++) {
            int dh = tap / 3 - 1, dw = tap % 3 - 1;
            int nh = h + dh, nw = w + dw;
            if (nh < 0 || nh >= H || nw < 0 || nw >= W) continue;
            long ns = site + (long)dh * W + dw;
            float i0 = b2f(xm[ns * 2 + 0]), i1 = b2f(xm[ns * 2 + 1]);
            const float* wp = Wt + tap * 32;
#pragma unroll
            for (int co = 0; co < 16; co++) acc[co] += i0 * wp[co] + i1 * wp[16 + co];
        }
    }
    st8(out + site * 16, acc);
    st8(out + site * 16 + 8, acc + 8);
}

// ---------------- MFMA direct conv 3x3 SAME (b-major sites) ----------------
template<int CIN, int CINP, int COUT, int KK, int MT_W, int NT_W, int H, int W>
__global__ void conv_mfma(const bf16* __restrict__ in, const bf16* __restrict__ wb,
                          const float* __restrict__ mask, bf16* __restrict__ out) {
    constexpr int NT = COUT / 16;
    constexpr int NWN = NT / NT_W;
    const int tid = threadIdx.x;
    const int wv = tid >> 6;
    const int L  = tid & 63;
    const int q  = (L >> 4);
    const int lm = L & 15;
    const int wn = wv % NWN;
    const int wm = wv / NWN;
    const int mt0 = wm * MT_W;
    const long base = (long)blockIdx.x * 64;

    int hh[MT_W], ww[MT_W];
    long siteA[MT_W];
#pragma unroll
    for (int i = 0; i < MT_W; i++) {
        long s = base + (mt0 + i) * 16 + lm;
        siteA[i] = s;
        int wq = (int)(s % W); long t2 = s / W;
        hh[i] = (int)(t2 % H); ww[i] = wq;
    }

    f4v acc[MT_W][NT_W];
#pragma unroll
    for (int i = 0; i < MT_W; i++)
#pragma unroll
        for (int j = 0; j < NT_W; j++) acc[i][j] = (f4v){0.f, 0.f, 0.f, 0.f};

    for (int tap = 0; tap < 9; tap++) {
        const int dh = tap / 3 - 1, dw = tap % 3 - 1;
#pragma unroll
        for (int kk = 0; kk < KK; kk++) {
            s8v a[MT_W];
#pragma unroll
            for (int i = 0; i < MT_W; i++) {
                int nh = hh[i] + dh, nw = ww[i] + dw;
                bool ok = (nh >= 0) & (nh < H) & (nw >= 0) & (nw < W);
                a[i] = (s8v){0, 0, 0, 0, 0, 0, 0, 0};
                if (ok) {
                    long ns = siteA[i] + (long)dh * W + dw;
                    a[i] = *(const s8v*)(in + ns * CIN + kk * 32 + q * 8);
                }
            }
#pragma unroll
            for (int j = 0; j < NT_W; j++) {
                int co = (wn * NT_W + j) * 16 + lm;
                s8v b = *(const s8v*)(wb + ((long)(tap * COUT + co)) * CINP + kk * 32 + q * 8);
#pragma unroll
                for (int i = 0; i < MT_W; i++)
                    acc[i][j] = __builtin_amdgcn_mfma_f32_16x16x32_bf16(a[i], b, acc[i][j], 0, 0, 0);
            }
        }
    }
#pragma unroll
    for (int i = 0; i < MT_W; i++) {
#pragma unroll
        for (int r = 0; r < 4; r++) {
            long so = base + (mt0 + i) * 16 + q * 4 + r;
            float mk = mask[so];
#pragma unroll
            for (int j = 0; j < NT_W; j++) {
                int co = (wn * NT_W + j) * 16 + lm;
                out[so * COUT + co] = f2b(mk > 0.f ? acc[i][j][r] : 0.f);
            }
        }
    }
}

// ---------------- BN stats ----------------
template<int C>
__global__ void bn_stats(const bf16* __restrict__ v, const float* __restrict__ mask,
                         float* __restrict__ sum, float* __restrict__ sumsq,
                         float* __restrict__ count, long nsites) {
    __shared__ float s_sum[C], s_ss[C];
    __shared__ float s_cnt;
    int tid = threadIdx.x;
    if (tid < C) { s_sum[tid] = 0.f; s_ss[tid] = 0.f; }
    if (tid == 0) s_cnt = 0.f;
    __syncthreads();
    const long total8 = nsites * C / 8;
    const long stride = (long)gridDim.x * 256;
    const int c0 = (int)((((long)blockIdx.x * 256 + tid) * 8) % C);
    float ls[8], lss[8];
#pragma unroll
    for (int i = 0; i < 8; i++) { ls[i] = 0.f; lss[i] = 0.f; }
    float lc = 0.f;
    for (long e8 = (long)blockIdx.x * 256 + tid; e8 < total8; e8 += stride) {
        long e0 = e8 * 8;
        float f[8];
        ld8(v + e0, f);
#pragma unroll
        for (int i = 0; i < 8; i++) { ls[i] += f[i]; lss[i] += f[i] * f[i]; }
        if (count != nullptr && c0 == 0) lc += (mask[e0 / C] > 0.f) ? 1.f : 0.f;
    }
#pragma unroll
    for (int i = 0; i < 8; i++) {
        atomicAdd(&s_sum[c0 + i], ls[i]);
        atomicAdd(&s_ss[c0 + i], lss[i]);
    }
    if (count != nullptr && c0 == 0) atomicAdd(&s_cnt, lc);
    __syncthreads();
    if (tid < C) { atomicAdd(&sum[tid], s_sum[tid]); atomicAdd(&sumsq[tid], s_ss[tid]); }
    if (count != nullptr && tid == 0) atomicAdd(count, s_cnt);
}

template<int C>
__global__ void bn_param(const float* __restrict__ sum, const float* __restrict__ ss,
                         const float* __restrict__ count,
                         const float* __restrict__ g, const float* __restrict__ b,
                         float* __restrict__ scale, float* __restrict__ shift) {
    int c = threadIdx.x;
    if (c >= C) return;
    float n = fmaxf(count[0], 1.f);
    float mean = sum[c] / n;
    float var  = ss[c] / n - mean * mean;
    float sc = (1.f / sqrtf(var + 1e-4f)) * g[c];
    scale[c] = sc;
    shift[c] = b[c] - mean * sc;
}

// ---------------- BN apply (layers feeding convs directly: C=16, C=64) ----------------
template<int C>
__global__ void bn_apply(bf16* __restrict__ v, const float* __restrict__ mask,
                         const float* __restrict__ scale, const float* __restrict__ shift,
                         long nsites) {
    long i8 = (long)blockIdx.x * 256 + threadIdx.x;
    if (i8 >= nsites * C / 8) return;
    long e0 = i8 * 8;
    int c0 = (int)(e0 % C);
    long site = e0 / C;
    float mk = mask[site];
    float f[8], o[8];
    ld8(v + e0, f);
#pragma unroll
    for (int i = 0; i < 8; i++)
        o[i] = (mk > 0.f) ? fmaxf(f[i] * scale[c0 + i] + shift[c0 + i], 0.f) : 0.f;
    st8(v + e0, o);
}

// ---------------- maxpool + fused BN affine/relu (C=32, b-major output) ----------------
template<int C>
__global__ void maxpool_bn(const bf16* __restrict__ in, const float* __restrict__ min_,
                           const float* __restrict__ scale, const float* __restrict__ shift,
                           bf16* __restrict__ out, float* __restrict__ mout,
                           int B, int H, int W, int OH, int OW) {
    long i8 = (long)blockIdx.x * 256 + threadIdx.x;
    long total8 = (long)B * OH * OW * C / 8;
    if (i8 >= total8) return;
    long e0 = i8 * 8;
    int c0 = (int)(e0 % C);
    long osite = e0 / C;
    int ow = (int)(osite % OW); long t2 = osite / OW; int oh = (int)(t2 % OH); long b = t2 / OH;
    float sc[8], sh[8];
#pragma unroll
    for (int i = 0; i < 8; i++) { sc[i] = scale[c0 + i]; sh[i] = shift[c0 + i]; }
    float mm = 0.f, p[8];
#pragma unroll
    for (int i = 0; i < 8; i++) p[i] = -1e30f;
    for (int kh = 0; kh < 3; kh++)
    for (int kw = 0; kw < 3; kw++) {
        int h = oh * 2 + kh, w = ow * 2 + kw;
        long is = ((long)b * H + h) * W + w;
        float mv = min_[is];
        if (mv > 0.f) {
            mm = 1.f;
            float f[8];
            ld8(in + is * C + c0, f);
#pragma unroll
            for (int i = 0; i < 8; i++) p[i] = fmaxf(p[i], f[i] * sc[i] + sh[i]);
        }
    }
    float o[8];
#pragma unroll
    for (int i = 0; i < 8; i++) o[i] = (mm > 0.f) ? fmaxf(p[i], 0.f) : 0.f;
    st8(out + e0, o);
    if (c0 == 0) mout[osite] = mm;
}

// ---------------- maxpool2 + fused BN4: c4[b-major][128] -> p2T8[k8][hw][b][8], m2h[hw*2048+b] ----------------
__global__ void maxpool_p2t(const bf16* __restrict__ c4, const float* __restrict__ m1,
                            const float* __restrict__ scale, const float* __restrict__ shift,
                            bf16* __restrict__ p2T8, float* __restrict__ m2h) {
    int t = blockIdx.x * 256 + threadIdx.x;          // 16*35*2048 = 1,146,880
    if (t >= 1146880) return;
    int b  = t & 2047;
    int q2 = t >> 11;
    int hw = q2 % 35;
    int k8 = q2 / 35;
    int oh = hw / QW, ow = hw % QW;
    int c0 = k8 * 8;
    float sc[8], sh[8];
#pragma unroll
    for (int i = 0; i < 8; i++) { sc[i] = scale[c0 + i]; sh[i] = shift[c0 + i]; }
    float mm = 0.f, p[8];
#pragma unroll
    for (int i = 0; i < 8; i++) p[i] = -1e30f;
    for (int kh = 0; kh < 3; kh++)
    for (int kw = 0; kw < 3; kw++) {
        int h = oh * 2 + kh, w = ow * 2 + kw;
        long is = ((long)b * PH + h) * PW + w;
        float mv = m1[is];
        if (mv > 0.f) {
            mm = 1.f;
            float f[8];
            ld8(c4 + is * 128 + c0, f);
#pragma unroll
            for (int i = 0; i < 8; i++) p[i] = fmaxf(p[i], f[i] * sc[i] + sh[i]);
        }
    }
    float o[8];
#pragma unroll
    for (int i = 0; i < 8; i++) o[i] = (mm > 0.f) ? fmaxf(p[i], 0.f) : 0.f;
    st8(p2T8 + (long)t * 8, o);                      // t == (k8*35+hw)*2048+b exactly
    if (k8 == 0) m2h[hw * 2048 + b] = mm;
}

// ---------------- ConvLSTM gates v3: hw-uniform blocks, coalesced A (p2T8), channel-split ----------------
// grid = 2240 site-groups x 2 channel-halves. Block: 32 b's at one hw, 128 channels.
// Wave wv owns cc_local = wv*2+j (j=0,1); cc_global = half*8+cc_local. acc[2][2][3] = 48 AGPR.
__global__ void __launch_bounds__(256, 3)
gates_mfma(const bf16* __restrict__ p2T8, const bf16* __restrict__ wbl3,
           const float* __restrict__ bl, const float* __restrict__ m2h,
           bf16* __restrict__ goutT8) {
    __shared__ bf16 sm[32][136];                     // pad to soften copy-phase bank conflicts
    const int bi = blockIdx.x;
    const int half = bi & 1;
    const int g2 = bi >> 1;                          // 0..2239
    const int hw = g2 >> 6;                          // /64
    const int b0 = (g2 & 63) * 32;
    const int h = hw / QW, w = hw % QW;
    const int tid = threadIdx.x;
    const int wv = tid >> 6;
    const int L  = tid & 63;
    const int q  = L >> 4;
    const int lm = L & 15;

    f4v acc[2][2][3];
#pragma unroll
    for (int i = 0; i < 2; i++)
#pragma unroll
        for (int j = 0; j < 2; j++)
#pragma unroll
            for (int g = 0; g < 3; g++) acc[i][j][g] = (f4v){0.f, 0.f, 0.f, 0.f};

    for (int tap = 0; tap < 9; tap++) {
        const int dh = tap / 3 - 1, dw = tap % 3 - 1;
        const int nh = h + dh, nw = w + dw;
        const bool ok = (nh >= 0) & (nh < QH) & (nw >= 0) & (nw < QW);   // block-uniform
        const int hwn = hw + dh * QW + dw;
#pragma unroll
        for (int kk = 0; kk < 4; kk++) {
            s8v a[2];
#pragma unroll
            for (int i = 0; i < 2; i++) {
                a[i] = (s8v){0, 0, 0, 0, 0, 0, 0, 0};
                if (ok) {
                    long idx = ((long)((kk * 4 + q) * 35 + hwn)) * 2048 + b0 + i * 16 + lm;
                    a[i] = *(const s8v*)(p2T8 + idx * 8);
                }
            }
            const bf16* slab = wbl3 + ((long)(tap * 4 + kk)) * 768 * 32 + (long)q * 8;
#pragma unroll
            for (int j = 0; j < 2; j++) {
                int cc = half * 8 + wv * 2 + j;       // 0..15
#pragma unroll
                for (int g = 0; g < 3; g++) {
                    int n = g * 256 + cc * 16 + lm;
                    s8v b = *(const s8v*)(slab + (long)n * 32);
#pragma unroll
                    for (int i = 0; i < 2; i++)
                        acc[i][j][g] = __builtin_amdgcn_mfma_f32_16x16x32_bf16(a[i], b, acc[i][j][g], 0, 0, 0);
                }
            }
        }
    }
    // LSTM epilogue -> LDS
#pragma unroll
    for (int j = 0; j < 2; j++) {
        int cc = half * 8 + wv * 2 + j;
        int c = cc * 16 + lm;                        // global channel 0..255
        int cl = (wv * 2 + j) * 16 + lm;             // local 0..127
        float bi_ = bl[c], bo_ = bl[512 + c], bg_ = bl[768 + c];
#pragma unroll
        for (int i = 0; i < 2; i++) {
#pragma unroll
            for (int r = 0; r < 4; r++) {
                int b_in = i * 16 + q * 4 + r;
                float m = m2h[hw * 2048 + b0 + b_in];
                float val = 0.f;
                if (m > 0.f) {
                    float iv = acc[i][j][0][r] + bi_;
                    float ov = acc[i][j][1][r] + bo_;
                    float gv = acc[i][j][2][r] + bg_;
                    float ct = sigmoidf_(iv) * tanhf(gv);
                    val = sigmoidf_(ov) * tanhf(ct);
                }
                sm[b_in][cl] = f2b(val);
            }
        }
    }
    __syncthreads();
    // coalesced copy LDS -> goutT8: 512 x 16B entries; entry e: c8l = e>>5, b_in = e&31
#pragma unroll
    for (int k = 0; k < 2; k++) {
        int e = k * 256 + tid;
        int c8l = e >> 5, b_in = e & 31;
        union { uint4 u; bf16 h8[8]; } v;
#pragma unroll
        for (int i = 0; i < 8; i++) v.h8[i] = sm[b_in][c8l * 8 + i];
        long dst = ((long)(hw * 32 + half * 16 + c8l)) * 2048 + b0 + b_in;
        *(uint4*)(goutT8 + dst * 8) = v.u;
    }
}

// ---------------- FC1 via MFMA, T8 layouts (fully coalesced fragment loads) ----------------
__global__ void fc1_mfma(const bf16* __restrict__ AT8, const bf16* __restrict__ WT8,
                         const float* __restrict__ lb1, bf16* __restrict__ y1) {
    const int tid = threadIdx.x;
    const int wv = tid >> 6;
    const int L  = tid & 63;
    const int q  = L >> 4, lm = L & 15;
    const int wm = wv >> 1, wn = wv & 1;
    const int bm = blockIdx.x & 31;
    const int bn = blockIdx.x >> 5;
    const int m0 = bm * 64 + wm * 32;
    const int n0 = bn * 64 + wn * 32;

    f4v acc[2][2];
#pragma unroll
    for (int i = 0; i < 2; i++)
#pragma unroll
        for (int j = 0; j < 2; j++) acc[i][j] = (f4v){0.f, 0.f, 0.f, 0.f};

#pragma unroll 2
    for (int k8 = 0; k8 < 1120; k8 += 4) {
        long ar = ((long)(k8 + q)) * 2048;
        long br = ((long)(k8 + q)) * 1024;
        s8v a0 = *(const s8v*)(AT8 + (ar + m0 + lm) * 8);
        s8v a1 = *(const s8v*)(AT8 + (ar + m0 + 16 + lm) * 8);
        s8v b0 = *(const s8v*)(WT8 + (br + n0 + lm) * 8);
        s8v b1 = *(const s8v*)(WT8 + (br + n0 + 16 + lm) * 8);
        acc[0][0] = __builtin_amdgcn_mfma_f32_16x16x32_bf16(a0, b0, acc[0][0], 0, 0, 0);
        acc[0][1] = __builtin_amdgcn_mfma_f32_16x16x32_bf16(a0, b1, acc[0][1], 0, 0, 0);
        acc[1][0] = __builtin_amdgcn_mfma_f32_16x16x32_bf16(a1, b0, acc[1][0], 0, 0, 0);
        acc[1][1] = __builtin_amdgcn_mfma_f32_16x16x32_bf16(a1, b1, acc[1][1], 0, 0, 0);
    }
#pragma unroll
    for (int i = 0; i < 2; i++) {
#pragma unroll
        for (int j = 0; j < 2; j++) {
            int nn = n0 + j * 16 + lm;
            float bias = lb1[nn];
#pragma unroll
            for (int r = 0; r < 4; r++) {
                int mm = m0 + i * 16 + q * 4 + r;
                y1[(long)mm * 1024 + nn] = f2b(fmaxf(acc[i][j][r] + bias, 0.f));
            }
        }
    }
}

// ---------------- FC2 ----------------
__global__ void fc2_k(const bf16* __restrict__ y1, const float* __restrict__ lw2,
                      const float* __restrict__ lb2, float* __restrict__ out) {
    long idx = (long)blockIdx.x * 256 + threadIdx.x;
    long total = (long)BB * 420;
    if (idx >= total) return;
    int j = (int)(idx % 420); long b = idx / 420;
    float acc = lb2[j];
    const bf16* yr = y1 + b * 1024;
    for (int k8 = 0; k8 < 1024; k8 += 8) {
        float f[8];
        ld8(yr + k8, f);
#pragma unroll
        for (int i = 0; i < 8; i++) acc += f[i] * lw2[(long)(k8 + i) * 420 + j];
    }
    out[idx] = acc;
}

// ---------------- launch ----------------
extern "C" void kernel_launch(void* const* d_in, const int* in_sizes, int n_in,
                              void* d_out, int out_size, void* d_ws, size_t ws_size,
                              hipStream_t stream) {
    const float* x    = (const float*)d_in[0];
    const int*   mask = (const int*)d_in[1];
    const float* W1 = (const float*)d_in[2];
    const float* g1 = (const float*)d_in[3];
    const float* b1 = (const float*)d_in[4];
    const float* W2 = (const float*)d_in[5];
    const float* g2 = (const float*)d_in[6];
    const float* b2 = (const float*)d_in[7];
    const float* W3 = (const float*)d_in[8];
    const float* g3 = (const float*)d_in[9];
    const float* b3 = (const float*)d_in[10];
    const float* W4 = (const float*)d_in[11];
    const float* g4 = (const float*)d_in[12];
    const float* b4 = (const float*)d_in[13];
    const float* Wl = (const float*)d_in[14];
    const float* bl = (const float*)d_in[15];
    const float* lw1 = (const float*)d_in[16];
    const float* lb1 = (const float*)d_in[17];
    const float* lw2 = (const float*)d_in[18];
    const float* lb2 = (const float*)d_in[19];
    float* out = (float*)d_out;

    float* ws = (float*)d_ws;
    float* m0 = ws + OFF_M0;
    float* m1 = ws + OFF_M1;
    float* m2h = ws + OFF_M2;
    bf16* bufA = (bf16*)(ws + OFF_BF);
    bf16* bufB = bufA + SZ_A;

    bf16* c1     = bufA;          // [NSITE1,16]
    bf16* xm     = bufB;          // [NSITE1,2]
    bf16* c2     = bufB;          // [NSITE1,32]
    bf16* p1     = bufA;          // [NSITE2,32]
    bf16* c3     = bufB;          // [NSITE2,64]
    bf16* c4     = bufA;          // [NSITE2,128]
    bf16* p2T8   = bufB;          // [16][35][2048][8] = 9,175,040
    bf16* goutT8 = bufA;          // [1120][2048][8]  = 18,350,080
    bf16* y1     = bufB;          // [2048,1024]
    bf16* wb2    = bufA + WB2_A;
    bf16* wb3    = bufB + WB3_B;
    bf16* wb4    = bufB + WB4_B;
    bf16* wbl3   = bufA + WBL_A;
    bf16* wfc1   = bufB + WFC1_B;

    hipMemsetAsync(ws, 0, 4096, stream);   // BN stat accumulators

    prep_k<<<(int)((NSITE1 + 255) / 256), 256, 0, stream>>>(x, mask, m0, xm);
    cvt_w_k<<<(9216 + 255) / 256, 256, 0, stream>>>(W2, wb2, 16, 32, 32, 9216);

    conv1_k<<<(int)((NSITE1 + 255) / 256), 256, 0, stream>>>(xm, W1, m0, c1);
    bn_stats<16><<<1280, 256, 0, stream>>>(c1, m0, ws + OFF_S1, ws + OFF_Q1, ws + OFF_N1, NSITE1);
    bn_param<16><<<1, 16, 0, stream>>>(ws + OFF_S1, ws + OFF_Q1, ws + OFF_N1, g1, b1, ws + OFF_SC1, ws + OFF_SH1);
    bn_apply<16><<<(int)(NSITE1 * 16 / 8 / 256), 256, 0, stream>>>(c1, m0, ws + OFF_SC1, ws + OFF_SH1, NSITE1);

    conv_mfma<16, 32, 32, 1, 2, 1, IH, IW><<<(int)(NSITE1 / 64), 256, 0, stream>>>(c1, wb2, m0, c2);
    bn_stats<32><<<1280, 256, 0, stream>>>(c2, m0, ws + OFF_S2, ws + OFF_Q2, nullptr, NSITE1);
    bn_param<32><<<1, 32, 0, stream>>>(ws + OFF_S2, ws + OFF_Q2, ws + OFF_N1, g2, b2, ws + OFF_SC2, ws + OFF_SH2);

    // fused BN2 + pool1
    maxpool_bn<32><<<(int)(NSITE2 * 32 / 8 / 256), 256, 0, stream>>>(c2, m0, ws + OFF_SC2, ws + OFF_SH2,
                                                                     p1, m1, BB, IH, IW, PH, PW);

    // c2 (bufB) dead: convert wb3, wb4, wfc1T8 into bufB slack
    cvt_w_k<<<(18432 + 255) / 256, 256, 0, stream>>>(W3, wb3, 32, 32, 64, 18432);
    cvt_w_k<<<(73728 + 255) / 256, 256, 0, stream>>>(W4, wb4, 64, 64, 128, 73728);
    cvt_fc1T8_k<<<(1146880 + 255) / 256, 256, 0, stream>>>(lw1, wfc1);

    conv_mfma<32, 32, 64, 1, 4, 1, PH, PW><<<(int)(NSITE2 / 64), 256, 0, stream>>>(p1, wb3, m1, c3);
    bn_stats<64><<<1280, 256, 0, stream>>>(c3, m1, ws + OFF_S3, ws + OFF_Q3, ws + OFF_N2, NSITE2);
    bn_param<64><<<1, 64, 0, stream>>>(ws + OFF_S3, ws + OFF_Q3, ws + OFF_N2, g3, b3, ws + OFF_SC3, ws + OFF_SH3);
    bn_apply<64><<<(int)(NSITE2 * 64 / 8 / 256), 256, 0, stream>>>(c3, m1, ws + OFF_SC3, ws + OFF_SH3, NSITE2);

    conv_mfma<64, 64, 128, 2, 4, 2, PH, PW><<<(int)(NSITE2 / 64), 256, 0, stream>>>(c3, wb4, m1, c4);
    bn_stats<128><<<1280, 256, 0, stream>>>(c4, m1, ws + OFF_S4, ws + OFF_Q4, nullptr, NSITE2);
    bn_param<128><<<1, 128, 0, stream>>>(ws + OFF_S4, ws + OFF_Q4, ws + OFF_N2, g4, b4, ws + OFF_SC4, ws + OFF_SH4);

    // fused BN4 + pool2 -> p2T8 (k8-chunked, hw-major) + m2h
    maxpool_p2t<<<(1146880 + 255) / 256, 256, 0, stream>>>(c4, m1, ws + OFF_SC4, ws + OFF_SH4, p2T8, m2h);

    // c4 (bufA) dead: convert wbl3 into bufA past goutT8's end
    cvt_wl3_k<<<(884736 + 255) / 256, 256, 0, stream>>>(Wl, wbl3);

    gates_mfma<<<4480, 256, 0, stream>>>(p2T8, wbl3, bl, m2h, goutT8);

    fc1_mfma<<<512, 256, 0, stream>>>(goutT8, wfc1, lb1, y1);

    fc2_k<<<(int)((BB * 420L + 255) / 256), 256, 0, stream>>>(y1, lw2, lb2, out);
}

// Round 9
// 1471.226 us; speedup vs baseline: 1.7446x; 1.0315x over previous
//
#include <hip/hip_runtime.h>
#include <hip/hip_bf16.h>
#include <math.h>

using bf16 = __hip_bfloat16;

typedef short s8v __attribute__((ext_vector_type(8)));   // 8 bf16 bit-pattern (4 VGPRs)
typedef float f4v __attribute__((ext_vector_type(4)));   // MFMA accumulator

// ---------------- problem dims ----------------
static constexpr int  BB  = 2048;
static constexpr int  IH  = 23, IW = 31;   // stage 1 spatial
static constexpr int  PH  = 11, PW = 15;   // after pool1
static constexpr int  QH  = 5,  QW = 7;    // after pool2
static constexpr long NSITE1 = (long)BB * IH * IW;   // 1,460,224
static constexpr long NSITE2 = (long)BB * PH * PW;   //   337,920
static constexpr long NSITE3 = (long)BB * QH * QW;   //    71,680

// ---------------- workspace layout ----------------
static constexpr long OFF_S1 = 0,   OFF_Q1 = 64;
static constexpr long OFF_S2 = 128, OFF_Q2 = 192;
static constexpr long OFF_S3 = 256, OFF_Q3 = 320;
static constexpr long OFF_S4 = 384, OFF_Q4 = 512;
static constexpr long OFF_N1 = 640, OFF_N2 = 641;
static constexpr long OFF_SC1 = 704,  OFF_SH1 = 768;
static constexpr long OFF_SC2 = 832,  OFF_SH2 = 896;
static constexpr long OFF_SC3 = 960,  OFF_SH3 = 1024;
static constexpr long OFF_SC4 = 1088, OFF_SH4 = 1216;
static constexpr long OFF_M0 = 2048;
static constexpr long OFF_M1 = OFF_M0 + NSITE1;
static constexpr long OFF_M2 = OFF_M1 + NSITE2;      // m2h: hw-major mask [hw*2048+b]
static constexpr long OFF_BF = 1871872;              // float offset where bf16 area starts
static constexpr long SZ_A   = 43253760L;            // bf16 elems per region
static constexpr long WB2_A  = 25000000L;  // [9][32][32]
static constexpr long WB3_B  = 22000000L;  // [9][64][32]
static constexpr long WB4_B  = 22100000L;  // [9][128][64]
static constexpr long WBL_A  = 20000000L;  // [9][4][768][32] = 884,736
static constexpr long WFC1_B = 23000000L;  // wfc1T8 [1120][1024][8] = 9,175,040

__device__ __forceinline__ float sigmoidf_(float x) { return 1.f / (1.f + __expf(-x)); }
__device__ __forceinline__ float b2f(bf16 v) { return __bfloat162float(v); }
__device__ __forceinline__ bf16  f2b(float v) { return __float2bfloat16(v); }

__device__ __forceinline__ void ld8(const bf16* p, float* f) {
    union { uint4 u; unsigned short s[8]; } cv;
    cv.u = *(const uint4*)p;
#pragma unroll
    for (int i = 0; i < 8; i++) f[i] = __uint_as_float(((unsigned int)cv.s[i]) << 16);
}
__device__ __forceinline__ void st8(bf16* p, const float* f) {
    union { uint4 u; bf16 h[8]; } cv;
#pragma unroll
    for (int i = 0; i < 8; i++) cv.h[i] = f2b(f[i]);
    *(uint4*)p = cv.u;
}

// ---------------- weight convert: W[tap][cin][cout] f32 -> wb[tap][cout][cinp] bf16 ----------------
__global__ void cvt_w_k(const float* __restrict__ W, bf16* __restrict__ wb,
                        int CIN, int CINP, int COUT, int total) {
    int idx = blockIdx.x * 256 + threadIdx.x;
    if (idx >= total) return;
    int ci  = idx % CINP;
    int t2  = idx / CINP;
    int co  = t2 % COUT;
    int tap = t2 / COUT;
    wb[idx] = (ci < CIN) ? f2b(W[((long)(tap * CIN + ci)) * COUT + co]) : f2b(0.f);
}

// ---------------- LSTM weight: Wl[tap][cin][1024] -> wbl3[tap][kk][n'=g*256+c][32] ----------------
__global__ void cvt_wl3_k(const float* __restrict__ Wl, bf16* __restrict__ wbl3) {
    int idx = blockIdx.x * 256 + threadIdx.x;
    if (idx >= 884736) return;
    int kidx = idx & 31;
    int n    = (idx >> 5) % 768;
    int kk   = (idx >> 5) / 768 % 4;
    int tap  = idx / (32 * 768 * 4);
    int g = n >> 8, c = n & 255;
    int col = (g == 0) ? c : (g == 1 ? 512 + c : 768 + c);
    int cin = kk * 32 + kidx;
    wbl3[idx] = f2b(Wl[((long)(tap * 128 + cin)) * 1024 + col]);
}

// ---------------- FC1 weight: lw1[k=c*35+hw][j] f32 -> wfc1T8[k8g=hw*32+c8][j][8] bf16 ----------------
__global__ void cvt_fc1T8_k(const float* __restrict__ lw1, bf16* __restrict__ wfc1) {
    int t = blockIdx.x * 256 + threadIdx.x;          // 1120*1024 threads
    if (t >= 1146880) return;
    int j   = t & 1023;
    int k8g = t >> 10;
    int hw  = k8g >> 5;
    int c8  = k8g & 31;
    float f[8];
#pragma unroll
    for (int c7 = 0; c7 < 8; c7++)
        f[c7] = lw1[((long)((c8 * 8 + c7) * 35 + hw)) * 1024 + j];
    st8(wfc1 + (long)t * 8, f);
}

// ---------------- prep ----------------
__global__ void prep_k(const float* __restrict__ x, const int* __restrict__ mask,
                       float* __restrict__ m0, bf16* __restrict__ xm) {
    long idx = (long)blockIdx.x * 256 + threadIdx.x;
    if (idx >= NSITE1) return;
    float m = (mask[idx] != 0) ? 1.f : 0.f;
    m0[idx] = m;
    xm[idx * 2 + 0] = f2b(x[idx * 2 + 0] * m);
    xm[idx * 2 + 1] = f2b(x[idx * 2 + 1] * m);
}

// ---------------- conv1: 2->16 ----------------
__global__ void conv1_k(const bf16* __restrict__ xm, const float* __restrict__ Wt,
                        const float* __restrict__ m0, bf16* __restrict__ out) {
    const int H = IH, W = IW;
    long site = (long)blockIdx.x * 256 + threadIdx.x;
    if (site >= NSITE1) return;
    float acc[16];
#pragma unroll
    for (int i = 0; i < 16; i++) acc[i] = 0.f;
    float mk = m0[site];
    if (mk > 0.f) {
        int w = (int)(site % W); int h = (int)((site / W) % H);
        for (int tap = 0; tap < 9; tap++) {
            int dh = tap / 3 - 1, dw = tap % 3 - 1;
            int nh = h + dh, nw = w + dw;
            if (nh < 0 || nh >= H || nw < 0 || nw >= W) continue;
            long ns = site + (long)dh * W + dw;
            float i0 = b2f(xm[ns * 2 + 0]), i1 = b2f(xm[ns * 2 + 1]);
            const float* wp = Wt + tap * 32;
#pragma unroll
            for (int co = 0; co < 16; co++) acc[co] += i0 * wp[co] + i1 * wp[16 + co];
        }
    }
    st8(out + site * 16, acc);
    st8(out + site * 16 + 8, acc + 8);
}

// ---------------- MFMA direct conv 3x3 SAME (b-major sites) ----------------
template<int CIN, int CINP, int COUT, int KK, int MT_W, int NT_W, int H, int W>
__global__ void conv_mfma(const bf16* __restrict__ in, const bf16* __restrict__ wb,
                          const float* __restrict__ mask, bf16* __restrict__ out) {
    constexpr int NT = COUT / 16;
    constexpr int NWN = NT / NT_W;
    const int tid = threadIdx.x;
    const int wv = tid >> 6;
    const int L  = tid & 63;
    const int q  = (L >> 4);
    const int lm = L & 15;
    const int wn = wv % NWN;
    const int wm = wv / NWN;
    const int mt0 = wm * MT_W;
    const long base = (long)blockIdx.x * 64;

    int hh[MT_W], ww[MT_W];
    long siteA[MT_W];
#pragma unroll
    for (int i = 0; i < MT_W; i++) {
        long s = base + (mt0 + i) * 16 + lm;
        siteA[i] = s;
        int wq = (int)(s % W); long t2 = s / W;
        hh[i] = (int)(t2 % H); ww[i] = wq;
    }

    f4v acc[MT_W][NT_W];
#pragma unroll
    for (int i = 0; i < MT_W; i++)
#pragma unroll
        for (int j = 0; j < NT_W; j++) acc[i][j] = (f4v){0.f, 0.f, 0.f, 0.f};

    for (int tap = 0; tap < 9; tap++) {
        const int dh = tap / 3 - 1, dw = tap % 3 - 1;
#pragma unroll
        for (int kk = 0; kk < KK; kk++) {
            s8v a[MT_W];
#pragma unroll
            for (int i = 0; i < MT_W; i++) {
                int nh = hh[i] + dh, nw = ww[i] + dw;
                bool ok = (nh >= 0) & (nh < H) & (nw >= 0) & (nw < W);
                a[i] = (s8v){0, 0, 0, 0, 0, 0, 0, 0};
                if (ok) {
                    long ns = siteA[i] + (long)dh * W + dw;
                    a[i] = *(const s8v*)(in + ns * CIN + kk * 32 + q * 8);
                }
            }
#pragma unroll
            for (int j = 0; j < NT_W; j++) {
                int co = (wn * NT_W + j) * 16 + lm;
                s8v b = *(const s8v*)(wb + ((long)(tap * COUT + co)) * CINP + kk * 32 + q * 8);
#pragma unroll
                for (int i = 0; i < MT_W; i++)
                    acc[i][j] = __builtin_amdgcn_mfma_f32_16x16x32_bf16(a[i], b, acc[i][j], 0, 0, 0);
            }
        }
    }
#pragma unroll
    for (int i = 0; i < MT_W; i++) {
#pragma unroll
        for (int r = 0; r < 4; r++) {
            long so = base + (mt0 + i) * 16 + q * 4 + r;
            float mk = mask[so];
#pragma unroll
            for (int j = 0; j < NT_W; j++) {
                int co = (wn * NT_W + j) * 16 + lm;
                out[so * COUT + co] = f2b(mk > 0.f ? acc[i][j][r] : 0.f);
            }
        }
    }
}

// ---------------- BN stats ----------------
template<int C>
__global__ void bn_stats(const bf16* __restrict__ v, const float* __restrict__ mask,
                         float* __restrict__ sum, float* __restrict__ sumsq,
                         float* __restrict__ count, long nsites) {
    __shared__ float s_sum[C], s_ss[C];
    __shared__ float s_cnt;
    int tid = threadIdx.x;
    if (tid < C) { s_sum[tid] = 0.f; s_ss[tid] = 0.f; }
    if (tid == 0) s_cnt = 0.f;
    __syncthreads();
    const long total8 = nsites * C / 8;
    const long stride = (long)gridDim.x * 256;
    const int c0 = (int)((((long)blockIdx.x * 256 + tid) * 8) % C);
    float ls[8], lss[8];
#pragma unroll
    for (int i = 0; i < 8; i++) { ls[i] = 0.f; lss[i] = 0.f; }
    float lc = 0.f;
    for (long e8 = (long)blockIdx.x * 256 + tid; e8 < total8; e8 += stride) {
        long e0 = e8 * 8;
        float f[8];
        ld8(v + e0, f);
#pragma unroll
        for (int i = 0; i < 8; i++) { ls[i] += f[i]; lss[i] += f[i] * f[i]; }
        if (count != nullptr && c0 == 0) lc += (mask[e0 / C] > 0.f) ? 1.f : 0.f;
    }
#pragma unroll
    for (int i = 0; i < 8; i++) {
        atomicAdd(&s_sum[c0 + i], ls[i]);
        atomicAdd(&s_ss[c0 + i], lss[i]);
    }
    if (count != nullptr && c0 == 0) atomicAdd(&s_cnt, lc);
    __syncthreads();
    if (tid < C) { atomicAdd(&sum[tid], s_sum[tid]); atomicAdd(&sumsq[tid], s_ss[tid]); }
    if (count != nullptr && tid == 0) atomicAdd(count, s_cnt);
}

template<int C>
__global__ void bn_param(const float* __restrict__ sum, const float* __restrict__ ss,
                         const float* __restrict__ count,
                         const float* __restrict__ g, const float* __restrict__ b,
                         float* __restrict__ scale, float* __restrict__ shift) {
    int c = threadIdx.x;
    if (c >= C) return;
    float n = fmaxf(count[0], 1.f);
    float mean = sum[c] / n;
    float var  = ss[c] / n - mean * mean;
    float sc = (1.f / sqrtf(var + 1e-4f)) * g[c];
    scale[c] = sc;
    shift[c] = b[c] - mean * sc;
}

// ---------------- BN apply (layers feeding convs directly: C=16, C=64) ----------------
template<int C>
__global__ void bn_apply(bf16* __restrict__ v, const float* __restrict__ mask,
                         const float* __restrict__ scale, const float* __restrict__ shift,
                         long nsites) {
    long i8 = (long)blockIdx.x * 256 + threadIdx.x;
    if (i8 >= nsites * C / 8) return;
    long e0 = i8 * 8;
    int c0 = (int)(e0 % C);
    long site = e0 / C;
    float mk = mask[site];
    float f[8], o[8];
    ld8(v + e0, f);
#pragma unroll
    for (int i = 0; i < 8; i++)
        o[i] = (mk > 0.f) ? fmaxf(f[i] * scale[c0 + i] + shift[c0 + i], 0.f) : 0.f;
    st8(v + e0, o);
}

// ---------------- maxpool + fused BN affine/relu (C=32, b-major output) ----------------
template<int C>
__global__ void maxpool_bn(const bf16* __restrict__ in, const float* __restrict__ min_,
                           const float* __restrict__ scale, const float* __restrict__ shift,
                           bf16* __restrict__ out, float* __restrict__ mout,
                           int B, int H, int W, int OH, int OW) {
    long i8 = (long)blockIdx.x * 256 + threadIdx.x;
    long total8 = (long)B * OH * OW * C / 8;
    if (i8 >= total8) return;
    long e0 = i8 * 8;
    int c0 = (int)(e0 % C);
    long osite = e0 / C;
    int ow = (int)(osite % OW); long t2 = osite / OW; int oh = (int)(t2 % OH); long b = t2 / OH;
    float sc[8], sh[8];
#pragma unroll
    for (int i = 0; i < 8; i++) { sc[i] = scale[c0 + i]; sh[i] = shift[c0 + i]; }
    float mm = 0.f, p[8];
#pragma unroll
    for (int i = 0; i < 8; i++) p[i] = -1e30f;
    for (int kh = 0; kh < 3; kh++)
    for (int kw = 0; kw < 3; kw++) {
        int h = oh * 2 + kh, w = ow * 2 + kw;
        long is = ((long)b * H + h) * W + w;
        float mv = min_[is];
        if (mv > 0.f) {
            mm = 1.f;
            float f[8];
            ld8(in + is * C + c0, f);
#pragma unroll
            for (int i = 0; i < 8; i++) p[i] = fmaxf(p[i], f[i] * sc[i] + sh[i]);
        }
    }
    float o[8];
#pragma unroll
    for (int i = 0; i < 8; i++) o[i] = (mm > 0.f) ? fmaxf(p[i], 0.f) : 0.f;
    st8(out + e0, o);
    if (c0 == 0) mout[osite] = mm;
}

// ---------------- maxpool2 + fused BN4: c4[b-major][128] -> p2T8[k8][hw][b][8], m2h[hw*2048+b] ----------------
__global__ void maxpool_p2t(const bf16* __restrict__ c4, const float* __restrict__ m1,
                            const float* __restrict__ scale, const float* __restrict__ shift,
                            bf16* __restrict__ p2T8, float* __restrict__ m2h) {
    int t = blockIdx.x * 256 + threadIdx.x;          // 16*35*2048 = 1,146,880
    if (t >= 1146880) return;
    int b  = t & 2047;
    int q2 = t >> 11;
    int hw = q2 % 35;
    int k8 = q2 / 35;
    int oh = hw / QW, ow = hw % QW;
    int c0 = k8 * 8;
    float sc[8], sh[8];
#pragma unroll
    for (int i = 0; i < 8; i++) { sc[i] = scale[c0 + i]; sh[i] = shift[c0 + i]; }
    float mm = 0.f, p[8];
#pragma unroll
    for (int i = 0; i < 8; i++) p[i] = -1e30f;
    for (int kh = 0; kh < 3; kh++)
    for (int kw = 0; kw < 3; kw++) {
        int h = oh * 2 + kh, w = ow * 2 + kw;
        long is = ((long)b * PH + h) * PW + w;
        float mv = m1[is];
        if (mv > 0.f) {
            mm = 1.f;
            float f[8];
            ld8(c4 + is * 128 + c0, f);
#pragma unroll
            for (int i = 0; i < 8; i++) p[i] = fmaxf(p[i], f[i] * sc[i] + sh[i]);
        }
    }
    float o[8];
#pragma unroll
    for (int i = 0; i < 8; i++) o[i] = (mm > 0.f) ? fmaxf(p[i], 0.f) : 0.f;
    st8(p2T8 + (long)t * 8, o);                      // t == (k8*35+hw)*2048+b exactly
    if (k8 == 0) m2h[hw * 2048 + b] = mm;
}

// ---------------- ConvLSTM gates v4: 64 sites/block (2x B-reuse), hw-uniform, channel-split ----------------
// grid = 35 hw x 32 b-groups x 2 channel-halves = 2240. Block: 64 b's at one hw, 128 channels.
// Wave wv owns cc_local = wv*2+j; all waves cover 4 m-tiles. acc[4][2][3] = 96 AGPR.
// B-frags: contiguous 1KB wave-loads; per-block B traffic 864KB serves 64 sites (was 32).
__global__ void __launch_bounds__(256, 2)
gates_mfma(const bf16* __restrict__ p2T8, const bf16* __restrict__ wbl3,
           const float* __restrict__ bl, const float* __restrict__ m2h,
           bf16* __restrict__ goutT8) {
    __shared__ bf16 sm[64][136];
    const int bi = blockIdx.x;
    const int half = bi & 1;
    const int g2 = bi >> 1;                          // 0..1119
    const int hw = g2 >> 5;                          // /32
    const int b0 = (g2 & 31) * 64;
    const int h = hw / QW, w = hw % QW;
    const int tid = threadIdx.x;
    const int wv = tid >> 6;
    const int L  = tid & 63;
    const int q  = L >> 4;
    const int lm = L & 15;

    f4v acc[4][2][3];
#pragma unroll
    for (int i = 0; i < 4; i++)
#pragma unroll
        for (int j = 0; j < 2; j++)
#pragma unroll
            for (int g = 0; g < 3; g++) acc[i][j][g] = (f4v){0.f, 0.f, 0.f, 0.f};

    for (int tap = 0; tap < 9; tap++) {
        const int dh = tap / 3 - 1, dw = tap % 3 - 1;
        const int nh = h + dh, nw = w + dw;
        const bool ok = (nh >= 0) & (nh < QH) & (nw >= 0) & (nw < QW);   // block-uniform
        const int hwn = hw + dh * QW + dw;
#pragma unroll
        for (int kk = 0; kk < 4; kk++) {
            s8v a[4];
#pragma unroll
            for (int i = 0; i < 4; i++) {
                a[i] = (s8v){0, 0, 0, 0, 0, 0, 0, 0};
                if (ok) {
                    long idx = ((long)((kk * 4 + q) * 35 + hwn)) * 2048 + b0 + i * 16 + lm;
                    a[i] = *(const s8v*)(p2T8 + idx * 8);
                }
            }
            const bf16* slab = wbl3 + ((long)(tap * 4 + kk)) * 768 * 32 + (long)q * 8;
#pragma unroll
            for (int j = 0; j < 2; j++) {
                int cc = half * 8 + wv * 2 + j;       // 0..15
#pragma unroll
                for (int g = 0; g < 3; g++) {
                    int n = g * 256 + cc * 16 + lm;
                    s8v b = *(const s8v*)(slab + (long)n * 32);
#pragma unroll
                    for (int i = 0; i < 4; i++)
                        acc[i][j][g] = __builtin_amdgcn_mfma_f32_16x16x32_bf16(a[i], b, acc[i][j][g], 0, 0, 0);
                }
            }
        }
    }
    // LSTM epilogue -> LDS
#pragma unroll
    for (int j = 0; j < 2; j++) {
        int cc = half * 8 + wv * 2 + j;
        int c = cc * 16 + lm;                        // global channel 0..255
        int cl = (wv * 2 + j) * 16 + lm;             // local 0..127
        float bi_ = bl[c], bo_ = bl[512 + c], bg_ = bl[768 + c];
#pragma unroll
        for (int i = 0; i < 4; i++) {
#pragma unroll
            for (int r = 0; r < 4; r++) {
                int b_in = i * 16 + q * 4 + r;
                float m = m2h[hw * 2048 + b0 + b_in];
                float val = 0.f;
                if (m > 0.f) {
                    float iv = acc[i][j][0][r] + bi_;
                    float ov = acc[i][j][1][r] + bo_;
                    float gv = acc[i][j][2][r] + bg_;
                    float ct = sigmoidf_(iv) * tanhf(gv);
                    val = sigmoidf_(ov) * tanhf(ct);
                }
                sm[b_in][cl] = f2b(val);
            }
        }
    }
    __syncthreads();
    // coalesced copy LDS -> goutT8: 1024 x 16B entries; entry e: c8l = e>>6, b_in = e&63
#pragma unroll
    for (int k = 0; k < 4; k++) {
        int e = k * 256 + tid;
        int c8l = e >> 6, b_in = e & 63;
        union { uint4 u; bf16 h8[8]; } v;
#pragma unroll
        for (int i = 0; i < 8; i++) v.h8[i] = sm[b_in][c8l * 8 + i];
        long dst = ((long)(hw * 32 + half * 16 + c8l)) * 2048 + b0 + b_in;
        *(uint4*)(goutT8 + dst * 8) = v.u;
    }
}

// ---------------- FC1 via MFMA, T8 layouts (fully coalesced fragment loads) ----------------
__global__ void fc1_mfma(const bf16* __restrict__ AT8, const bf16* __restrict__ WT8,
                         const float* __restrict__ lb1, bf16* __restrict__ y1) {
    const int tid = threadIdx.x;
    const int wv = tid >> 6;
    const int L  = tid & 63;
    const int q  = L >> 4, lm = L & 15;
    const int wm = wv >> 1, wn = wv & 1;
    const int bm = blockIdx.x & 31;
    const int bn = blockIdx.x >> 5;
    const int m0 = bm * 64 + wm * 32;
    const int n0 = bn * 64 + wn * 32;

    f4v acc[2][2];
#pragma unroll
    for (int i = 0; i < 2; i++)
#pragma unroll
        for (int j = 0; j < 2; j++) acc[i][j] = (f4v){0.f, 0.f, 0.f, 0.f};

#pragma unroll 2
    for (int k8 = 0; k8 < 1120; k8 += 4) {
        long ar = ((long)(k8 + q)) * 2048;
        long br = ((long)(k8 + q)) * 1024;
        s8v a0 = *(const s8v*)(AT8 + (ar + m0 + lm) * 8);
        s8v a1 = *(const s8v*)(AT8 + (ar + m0 + 16 + lm) * 8);
        s8v b0 = *(const s8v*)(WT8 + (br + n0 + lm) * 8);
        s8v b1 = *(const s8v*)(WT8 + (br + n0 + 16 + lm) * 8);
        acc[0][0] = __builtin_amdgcn_mfma_f32_16x16x32_bf16(a0, b0, acc[0][0], 0, 0, 0);
        acc[0][1] = __builtin_amdgcn_mfma_f32_16x16x32_bf16(a0, b1, acc[0][1], 0, 0, 0);
        acc[1][0] = __builtin_amdgcn_mfma_f32_16x16x32_bf16(a1, b0, acc[1][0], 0, 0, 0);
        acc[1][1] = __builtin_amdgcn_mfma_f32_16x16x32_bf16(a1, b1, acc[1][1], 0, 0, 0);
    }
#pragma unroll
    for (int i = 0; i < 2; i++) {
#pragma unroll
        for (int j = 0; j < 2; j++) {
            int nn = n0 + j * 16 + lm;
            float bias = lb1[nn];
#pragma unroll
            for (int r = 0; r < 4; r++) {
                int mm = m0 + i * 16 + q * 4 + r;
                y1[(long)mm * 1024 + nn] = f2b(fmaxf(acc[i][j][r] + bias, 0.f));
            }
        }
    }
}

// ---------------- FC2 ----------------
__global__ void fc2_k(const bf16* __restrict__ y1, const float* __restrict__ lw2,
                      const float* __restrict__ lb2, float* __restrict__ out) {
    long idx = (long)blockIdx.x * 256 + threadIdx.x;
    long total = (long)BB * 420;
    if (idx >= total) return;
    int j = (int)(idx % 420); long b = idx / 420;
    float acc = lb2[j];
    const bf16* yr = y1 + b * 1024;
    for (int k8 = 0; k8 < 1024; k8 += 8) {
        float f[8];
        ld8(yr + k8, f);
#pragma unroll
        for (int i = 0; i < 8; i++) acc += f[i] * lw2[(long)(k8 + i) * 420 + j];
    }
    out[idx] = acc;
}

// ---------------- launch ----------------
extern "C" void kernel_launch(void* const* d_in, const int* in_sizes, int n_in,
                              void* d_out, int out_size, void* d_ws, size_t ws_size,
                              hipStream_t stream) {
    const float* x    = (const float*)d_in[0];
    const int*   mask = (const int*)d_in[1];
    const float* W1 = (const float*)d_in[2];
    const float* g1 = (const float*)d_in[3];
    const float* b1 = (const float*)d_in[4];
    const float* W2 = (const float*)d_in[5];
    const float* g2 = (const float*)d_in[6];
    const float* b2 = (const float*)d_in[7];
    const float* W3 = (const float*)d_in[8];
    const float* g3 = (const float*)d_in[9];
    const float* b3 = (const float*)d_in[10];
    const float* W4 = (const float*)d_in[11];
    const float* g4 = (const float*)d_in[12];
    const float* b4 = (const float*)d_in[13];
    const float* Wl = (const float*)d_in[14];
    const float* bl = (const float*)d_in[15];
    const float* lw1 = (const float*)d_in[16];
    const float* lb1 = (const float*)d_in[17];
    const float* lw2 = (const float*)d_in[18];
    const float* lb2 = (const float*)d_in[19];
    float* out = (float*)d_out;

    float* ws = (float*)d_ws;
    float* m0 = ws + OFF_M0;
    float* m1 = ws + OFF_M1;
    float* m2h = ws + OFF_M2;
    bf16* bufA = (bf16*)(ws + OFF_BF);
    bf16* bufB = bufA + SZ_A;

    bf16* c1     = bufA;          // [NSITE1,16]
    bf16* xm     = bufB;          // [NSITE1,2]
    bf16* c2     = bufB;          // [NSITE1,32]
    bf16* p1     = bufA;          // [NSITE2,32]
    bf16* c3     = bufB;          // [NSITE2,64]
    bf16* c4     = bufA;          // [NSITE2,128]
    bf16* p2T8   = bufB;          // [16][35][2048][8]
    bf16* goutT8 = bufA;          // [1120][2048][8]
    bf16* y1     = bufB;          // [2048,1024]
    bf16* wb2    = bufA + WB2_A;
    bf16* wb3    = bufB + WB3_B;
    bf16* wb4    = bufB + WB4_B;
    bf16* wbl3   = bufA + WBL_A;
    bf16* wfc1   = bufB + WFC1_B;

    hipMemsetAsync(ws, 0, 4096, stream);   // BN stat accumulators

    prep_k<<<(int)((NSITE1 + 255) / 256), 256, 0, stream>>>(x, mask, m0, xm);
    cvt_w_k<<<(9216 + 255) / 256, 256, 0, stream>>>(W2, wb2, 16, 32, 32, 9216);

    conv1_k<<<(int)((NSITE1 + 255) / 256), 256, 0, stream>>>(xm, W1, m0, c1);
    bn_stats<16><<<1280, 256, 0, stream>>>(c1, m0, ws + OFF_S1, ws + OFF_Q1, ws + OFF_N1, NSITE1);
    bn_param<16><<<1, 16, 0, stream>>>(ws + OFF_S1, ws + OFF_Q1, ws + OFF_N1, g1, b1, ws + OFF_SC1, ws + OFF_SH1);
    bn_apply<16><<<(int)(NSITE1 * 16 / 8 / 256), 256, 0, stream>>>(c1, m0, ws + OFF_SC1, ws + OFF_SH1, NSITE1);

    conv_mfma<16, 32, 32, 1, 2, 1, IH, IW><<<(int)(NSITE1 / 64), 256, 0, stream>>>(c1, wb2, m0, c2);
    bn_stats<32><<<1280, 256, 0, stream>>>(c2, m0, ws + OFF_S2, ws + OFF_Q2, nullptr, NSITE1);
    bn_param<32><<<1, 32, 0, stream>>>(ws + OFF_S2, ws + OFF_Q2, ws + OFF_N1, g2, b2, ws + OFF_SC2, ws + OFF_SH2);

    // fused BN2 + pool1
    maxpool_bn<32><<<(int)(NSITE2 * 32 / 8 / 256), 256, 0, stream>>>(c2, m0, ws + OFF_SC2, ws + OFF_SH2,
                                                                     p1, m1, BB, IH, IW, PH, PW);

    // c2 (bufB) dead: convert wb3, wb4, wfc1T8 into bufB slack
    cvt_w_k<<<(18432 + 255) / 256, 256, 0, stream>>>(W3, wb3, 32, 32, 64, 18432);
    cvt_w_k<<<(73728 + 255) / 256, 256, 0, stream>>>(W4, wb4, 64, 64, 128, 73728);
    cvt_fc1T8_k<<<(1146880 + 255) / 256, 256, 0, stream>>>(lw1, wfc1);

    conv_mfma<32, 32, 64, 1, 4, 1, PH, PW><<<(int)(NSITE2 / 64), 256, 0, stream>>>(p1, wb3, m1, c3);
    bn_stats<64><<<1280, 256, 0, stream>>>(c3, m1, ws + OFF_S3, ws + OFF_Q3, ws + OFF_N2, NSITE2);
    bn_param<64><<<1, 64, 0, stream>>>(ws + OFF_S3, ws + OFF_Q3, ws + OFF_N2, g3, b3, ws + OFF_SC3, ws + OFF_SH3);
    bn_apply<64><<<(int)(NSITE2 * 64 / 8 / 256), 256, 0, stream>>>(c3, m1, ws + OFF_SC3, ws + OFF_SH3, NSITE2);

    conv_mfma<64, 64, 128, 2, 4, 2, PH, PW><<<(int)(NSITE2 / 64), 256, 0, stream>>>(c3, wb4, m1, c4);
    bn_stats<128><<<1280, 256, 0, stream>>>(c4, m1, ws + OFF_S4, ws + OFF_Q4, nullptr, NSITE2);
    bn_param<128><<<1, 128, 0, stream>>>(ws + OFF_S4, ws + OFF_Q4, ws + OFF_N2, g4, b4, ws + OFF_SC4, ws + OFF_SH4);

    // fused BN4 + pool2 -> p2T8 (k8-chunked, hw-major) + m2h
    maxpool_p2t<<<(1146880 + 255) / 256, 256, 0, stream>>>(c4, m1, ws + OFF_SC4, ws + OFF_SH4, p2T8, m2h);

    // c4 (bufA) dead: convert wbl3 into bufA past goutT8's end
    cvt_wl3_k<<<(884736 + 255) / 256, 256, 0, stream>>>(Wl, wbl3);

    gates_mfma<<<2240, 256, 0, stream>>>(p2T8, wbl3, bl, m2h, goutT8);

    fc1_mfma<<<512, 256, 0, stream>>>(goutT8, wfc1, lb1, y1);

    fc2_k<<<(int)((BB * 420L + 255) / 256), 256, 0, stream>>>(y1, lw2, lb2, out);
}